// Round 4
// baseline (5729.939 us; speedup 1.0000x reference)
//
#include <hip/hip_runtime.h>
#include <math.h>

#define Bb 4
#define Ls 2048
#define Dd 1024
#define Hh 16
#define HDm 64
#define ML (Bb*Ls)   /* 8192 rows */

typedef double f64x4 __attribute__((ext_vector_type(4)));

// ---------------------------------------------------------------------------
// NT GEMM via f64 MFMA: C[m,n] = outscale * sum_k A[m,k]*B[n,k], f64 out.
// A,B f32 staged in LDS, cvt to f64 at fragment load; accumulate in f64
// matrix pipe. Block 256 = 4 waves; tile 64x64.
// MFMA f64 16x16x4 layouts (validated round 2): A row=lane&15, k=lane>>4;
// B col=lane&15, k=lane>>4; D row=4*reg+(lane>>4), col=lane&15.
// fp64 needed: logits sigma~1.1e6; fp32 projections give ~4e3 error -> fail.
// ---------------------------------------------------------------------------
__global__ __launch_bounds__(256) void gemm_nt_mfma_f64(
    const float* __restrict__ A, const float* __restrict__ B,
    double* __restrict__ C, double outscale) {
  const int N = Dd, K = Dd;
  __shared__ float As[64][17];
  __shared__ float Bs[64][17];
  const int tid = threadIdx.x;
  const int lane = tid & 63;
  const int w = tid >> 6;
  const int lrow = lane & 15, lk = lane >> 4;
  const int bm = blockIdx.y * 64, bn = blockIdx.x * 64;
  const int sr = tid >> 4, sc = tid & 15;   // staging coords

  f64x4 acc[4] = {{0.,0.,0.,0.},{0.,0.,0.,0.},{0.,0.,0.,0.},{0.,0.,0.,0.}};

  for (int k0 = 0; k0 < K; k0 += 16) {
#pragma unroll
    for (int i = 0; i < 4; i++) {
      int r = sr + 16 * i;
      As[r][sc] = A[(size_t)(bm + r) * K + k0 + sc];
      Bs[r][sc] = B[(size_t)(bn + r) * K + k0 + sc];
    }
    __syncthreads();
#pragma unroll
    for (int t = 0; t < 4; t++) {
      double a = (double)As[16 * w + lrow][4 * t + lk];
#pragma unroll
      for (int j = 0; j < 4; j++) {
        double bb = (double)Bs[16 * j + lrow][4 * t + lk];
        acc[j] = __builtin_amdgcn_mfma_f64_16x16x4f64(a, bb, acc[j], 0, 0, 0);
      }
    }
    __syncthreads();
  }
#pragma unroll
  for (int j = 0; j < 4; j++)
#pragma unroll
    for (int d = 0; d < 4; d++) {
      size_t m = (size_t)(bm + 16 * w + 4 * d + lk);
      C[m * N + bn + 16 * j + lrow] = acc[j][d] * outscale;
    }
}

// ---------------------------------------------------------------------------
// Same GEMM, f32 output + optional bias (f64 accumulate inside).
// ---------------------------------------------------------------------------
__global__ __launch_bounds__(256) void gemm_nt_mfma_f32(
    const float* __restrict__ A, const float* __restrict__ B,
    const float* __restrict__ bias, float* __restrict__ C) {
  const int N = Dd, K = Dd;
  __shared__ float As[64][17];
  __shared__ float Bs[64][17];
  const int tid = threadIdx.x;
  const int lane = tid & 63;
  const int w = tid >> 6;
  const int lrow = lane & 15, lk = lane >> 4;
  const int bm = blockIdx.y * 64, bn = blockIdx.x * 64;
  const int sr = tid >> 4, sc = tid & 15;

  f64x4 acc[4] = {{0.,0.,0.,0.},{0.,0.,0.,0.},{0.,0.,0.,0.},{0.,0.,0.,0.}};

  for (int k0 = 0; k0 < K; k0 += 16) {
#pragma unroll
    for (int i = 0; i < 4; i++) {
      int r = sr + 16 * i;
      As[r][sc] = A[(size_t)(bm + r) * K + k0 + sc];
      Bs[r][sc] = B[(size_t)(bn + r) * K + k0 + sc];
    }
    __syncthreads();
#pragma unroll
    for (int t = 0; t < 4; t++) {
      double a = (double)As[16 * w + lrow][4 * t + lk];
#pragma unroll
      for (int j = 0; j < 4; j++) {
        double bb = (double)Bs[16 * j + lrow][4 * t + lk];
        acc[j] = __builtin_amdgcn_mfma_f64_16x16x4f64(a, bb, acc[j], 0, 0, 0);
      }
    }
    __syncthreads();
  }
#pragma unroll
  for (int j = 0; j < 4; j++)
#pragma unroll
    for (int d = 0; d < 4; d++) {
      size_t m = (size_t)(bm + 16 * w + 4 * d + lk);
      int n = bn + 16 * j + lrow;
      float v = (float)acc[j][d];
      if (bias) v += bias[n];
      C[m * N + n] = v;
    }
}

// ---------------------------------------------------------------------------
// One-sweep flash attention, v6: v4 + async-stage prefetch, VGPR<=128.
// v5 FAILED THE BUDGET: hoisted ptr arrays + prefetch state -> VGPR 132;
// waves/CU halves at the 128 boundary (m69) -> occupancy 22.9->12.3%,
// 1710->2828us. v6 keeps the prefetch (v4 had ~2600cyc/tile unhidden
// staging latency) but pays for its 16 VGPRs:
//  - mref stored as float (always float-valued; expf(mo_f-ref_f) bit-equal
//    to v4's expf((float)(mo-ref)): f64 diff of float-valued doubles exact)
//  - fac[] gone (Oacc*=factor inside d-loop, same values/order)
//  - pP0/pP1[] gone (scalar ds_write_b32 into Ps inside d-loop; same slots,
//    wave-internal in-order; float4 reader unchanged)
//  - aout/stash addressing back inline (as v4)
// __launch_bounds__(256,4) pins the allocator to 128.
// LDS: Ks 16896 + Vs 8704 + Ps 10240 = 35840 B -> 4 blocks/CU.
// Softmax numerics bit-compatible with v4 (passed, absmax 48).
// ---------------------------------------------------------------------------
__global__ __launch_bounds__(256, 4) void attn_flash(
    double* __restrict__ Qd, const double* __restrict__ Kd,
    const float* __restrict__ Vf, float* __restrict__ attn,
    float* __restrict__ O) {
  __shared__ double Ks[32 * 66];
  __shared__ float  Vs[32 * 68];
  __shared__ float  Ps[4][32 * 20];   // per-wave P^T: [col 0..31][slot 0..15]

  const int tid = threadIdx.x;
  const int lane = tid & 63;
  const int w = tid >> 6;             // wave 0..3 -> q-row strip 16w
  const int lrow = lane & 15;         // A-row / B,D-col index
  const int lk = lane >> 4;           // k index / D row low bits
  const int blk = blockIdx.x;
  const int qt = blk & 31;            // 32 q-tiles of 64 rows
  const int h = (blk >> 5) & 15;
  const int b = blk >> 9;
  const int l0 = qt * 64;

  const double* Qg = Qd + ((size_t)(b * Ls + l0)) * Dd + h * HDm;
  const double* Kg = Kd + ((size_t)b * Ls) * Dd + h * HDm;
  const float*  Vg = Vf + ((size_t)b * Ls) * Dd + h * HDm;
  float* aout = attn + ((size_t)((b * Hh + h) * Ls + l0)) * Ls;

  // Q fragments: lane holds Q[16w+lrow][4t+lk] for t=0..15 (whole sweep);
  // Qd is pre-scaled by 0.125 at projection time.
  double qreg[16];
#pragma unroll
  for (int t = 0; t < 16; t++)
    qreg[t] = Qg[(size_t)(16 * w + lrow) * Dd + 4 * t + lk];

  // staging: thread (rb,c2) covers rows rb+8*it, cols 2*c2..2*c2+1
  const int c2 = tid & 31;
  const int rb = tid >> 5;
  const double* kptr = Kg + (size_t)rb * Dd + c2 * 2;
  const float*  vptr = Vg + (size_t)rb * Dd + c2 * 2;
  double* ksw = &Ks[rb * 66 + c2 * 2];   // + it*528 (8 rows * 66)
  float*  vsw = &Vs[rb * 68 + c2 * 2];   // + it*544 (8 rows * 68)

  double2 kreg[4];
  float2 vreg[4];
#pragma unroll
  for (int it = 0; it < 4; it++) {       // issue tile-0 loads
    kreg[it] = *(const double2*)(kptr + it * 8 * Dd);
    vreg[it] = *(const float2*)(vptr + it * 8 * Dd);
  }

  float mreff[4];
  double sacc[4];
  float Oacc[4][4];
#pragma unroll
  for (int d = 0; d < 4; d++) {
    mreff[d] = -INFINITY;
    sacc[d] = 0.0;
#pragma unroll
    for (int j = 0; j < 4; j++) Oacc[d][j] = 0.0f;
  }

  for (int kt = 0; kt < 64; kt++) {
    __syncthreads();  // prior tile's readers done
#pragma unroll
    for (int it = 0; it < 4; it++) {   // write prefetched regs (waits vmcnt)
      *(double2*)(ksw + it * 528) = kreg[it];
      *(float2*)(vsw + it * 544) = vreg[it];
    }
    __syncthreads();
    if (kt < 63) {                     // issue next tile's loads, no wait
      kptr += 32 * Dd;
      vptr += 32 * Dd;
#pragma unroll
      for (int it = 0; it < 4; it++) {
        kreg[it] = *(const double2*)(kptr + it * 8 * Dd);
        vreg[it] = *(const float2*)(vptr + it * 8 * Dd);
      }
    }

    // QK^T: E[r][c] = sum_k Q[r][k] K[c][k]; quadrant 0: keys 0-15, 1: 16-31
    f64x4 acc0 = {0.0, 0.0, 0.0, 0.0};
    f64x4 acc1 = {0.0, 0.0, 0.0, 0.0};
#pragma unroll
    for (int t = 0; t < 16; t++) {
      double b0 = Ks[lrow * 66 + 4 * t + lk];
      double b1 = Ks[(16 + lrow) * 66 + 4 * t + lk];
      acc0 = __builtin_amdgcn_mfma_f64_16x16x4f64(qreg[t], b0, acc0, 0, 0, 0);
      acc1 = __builtin_amdgcn_mfma_f64_16x16x4f64(qreg[t], b1, acc1, 0, 0, 0);
    }

    // online softmax per owned row: acc[d] is row 4*d + lk (f64 D layout),
    // col lrow (acc0) / 16+lrow (acc1). Logits pre-scaled via Q.
#pragma unroll
    for (int d = 0; d < 4; d++) {
      double e0 = acc0[d];
      double e1 = acc1[d];
      float tmf = fmaxf((float)e0, (float)e1);
#pragma unroll
      for (int m = 1; m < 16; m <<= 1) tmf = fmaxf(tmf, __shfl_xor(tmf, m));
      float mo_f = mreff[d];
      float ref_f = fmaxf(mo_f, tmf);        // float-rounded running ref
      double ref = (double)ref_f;
      float p0 = expf((float)(e0 - ref));
      float p1 = expf((float)(e1 - ref));
      double ts = (double)p0 + (double)p1;
#pragma unroll
      for (int m = 1; m < 16; m <<= 1) ts += __shfl_xor(ts, m);
      float factor = expf(mo_f - ref_f);     // <= 1
      sacc[d] = sacc[d] * (double)factor + ts;
      mreff[d] = ref_f;
#pragma unroll
      for (int j = 0; j < 4; j++) Oacc[d][j] *= factor;
      int row = 16 * w + 4 * d + lk;
      aout[(size_t)row * Ls + kt * 32 + lrow] = p0;
      aout[(size_t)row * Ls + kt * 32 + 16 + lrow] = p1;
      if (lrow == 0) {  // stash per-(row,tile) ref in dead Qd slice
        ((float*)(Qd + ((size_t)(b * Ls + l0 + row)) * Dd + h * HDm))[kt] = ref_f;
      }
      // P^T scalar writes: slot 4*lk+d holds row 4*d+lk of col lrow (/+16)
      Ps[w][lrow * 20 + 4 * lk + d] = p0;
      Ps[w][(16 + lrow) * 20 + 4 * lk + d] = p1;
    }

    // PV: lane owns rows 4*d+lk x dims 4*lrow+j; p broadcast from Ps
    // (reader float4 at 4*lk recovers its own softmax rows 4*d+lk)
#pragma unroll
    for (int t = 0; t < 32; t++) {
      float4 pb = *(const float4*)(&Ps[w][t * 20 + 4 * lk]);
      float4 vv = *(const float4*)(&Vs[t * 68 + lrow * 4]);
      Oacc[0][0] = fmaf(pb.x, vv.x, Oacc[0][0]);
      Oacc[0][1] = fmaf(pb.x, vv.y, Oacc[0][1]);
      Oacc[0][2] = fmaf(pb.x, vv.z, Oacc[0][2]);
      Oacc[0][3] = fmaf(pb.x, vv.w, Oacc[0][3]);
      Oacc[1][0] = fmaf(pb.y, vv.x, Oacc[1][0]);
      Oacc[1][1] = fmaf(pb.y, vv.y, Oacc[1][1]);
      Oacc[1][2] = fmaf(pb.y, vv.z, Oacc[1][2]);
      Oacc[1][3] = fmaf(pb.y, vv.w, Oacc[1][3]);
      Oacc[2][0] = fmaf(pb.z, vv.x, Oacc[2][0]);
      Oacc[2][1] = fmaf(pb.z, vv.y, Oacc[2][1]);
      Oacc[2][2] = fmaf(pb.z, vv.z, Oacc[2][2]);
      Oacc[2][3] = fmaf(pb.z, vv.w, Oacc[2][3]);
      Oacc[3][0] = fmaf(pb.w, vv.x, Oacc[3][0]);
      Oacc[3][1] = fmaf(pb.w, vv.y, Oacc[3][1]);
      Oacc[3][2] = fmaf(pb.w, vv.z, Oacc[3][2]);
      Oacc[3][3] = fmaf(pb.w, vv.w, Oacc[3][3]);
    }
  }

  // epilogue: normalize O, stash final ref + sum per row (row = 4*d + lk)
#pragma unroll
  for (int d = 0; d < 4; d++) {
    int row = 16 * w + 4 * d + lk;
    float sv = (float)(1.0 / sacc[d]);
    float4 ov = make_float4(Oacc[d][0] * sv, Oacc[d][1] * sv,
                            Oacc[d][2] * sv, Oacc[d][3] * sv);
    *(float4*)(O + ((size_t)(b * Ls + l0 + row)) * Dd + h * HDm + lrow * 4) = ov;
    if (lrow == 0) {
      float* mrow = (float*)(Qd + ((size_t)(b * Ls + l0 + row)) * Dd + h * HDm);
      mrow[64] = mreff[d];
      *(double*)(mrow + 66) = sacc[d];
    }
  }
}

// ---------------------------------------------------------------------------
// Rescale: p = p~ * exp(ref_t - ref_final) / s. One block per attention row.
// ---------------------------------------------------------------------------
__global__ __launch_bounds__(256) void attn_scale(
    float* __restrict__ attn, const double* __restrict__ Qd) {
  int R = blockIdx.x;                 // 0..131071: ((b*Hh+h)*Ls + l)
  int b = R >> 15;
  int rem = R & 32767;
  int h = rem >> 11;
  int l = rem & 2047;
  const float* mrow = (const float*)(Qd + ((size_t)(b * Ls + l)) * Dd + h * HDm);
  int tid = threadIdx.x;
  int kt = tid >> 2;                  // 8 cols per thread, within one 32-col tile
  double mt = (double)mrow[kt];
  double mf = (double)mrow[64];
  double s = *(const double*)(mrow + 66);
  float sc = (float)(exp(mt - mf) / s);
  float4* ap = (float4*)(attn + (size_t)R * Ls + tid * 8);
  float4 a0 = ap[0], a1 = ap[1];
  a0.x *= sc; a0.y *= sc; a0.z *= sc; a0.w *= sc;
  a1.x *= sc; a1.y *= sc; a1.z *= sc; a1.w *= sc;
  ap[0] = a0; ap[1] = a1;
}

// ---------------------------------------------------------------------------
extern "C" void kernel_launch(void* const* d_in, const int* in_sizes, int n_in,
                              void* d_out, int out_size, void* d_ws, size_t ws_size,
                              hipStream_t stream) {
  const float* query = (const float*)d_in[0];
  const float* key   = (const float*)d_in[1];
  const float* value = (const float*)d_in[2];
  const float* Wq    = (const float*)d_in[3];
  const float* Wk    = (const float*)d_in[4];
  const float* Wv    = (const float*)d_in[5];
  const float* Wo    = (const float*)d_in[6];
  const float* bo    = (const float*)d_in[7];

  float* out0 = (float*)d_out;            // [B,L,D]
  float* attn = out0 + (size_t)ML * Dd;   // [B,H,L,L]

  // ws: Qd (64MB f64) | Kd (64MB f64) | Vf (32MB f32) | Of (32MB f32)
  char* ws = (char*)d_ws;
  double* Qd = (double*)ws;
  double* Kd = (double*)(ws + (size_t)ML * Dd * 8);
  float*  Vf = (float*)(ws + (size_t)ML * Dd * 16);
  float*  Of = (float*)(ws + (size_t)ML * Dd * 16 + (size_t)ML * Dd * 4);

  dim3 gemm_grid(Dd / 64, ML / 64);
  // Q pre-scaled by softmax 1/sqrt(64) = 0.125 (exact pow2 -> logits
  // bit-identical to post-scaling)
  gemm_nt_mfma_f64<<<gemm_grid, 256, 0, stream>>>(query, Wq, Qd, 0.125);
  gemm_nt_mfma_f64<<<gemm_grid, 256, 0, stream>>>(key,   Wk, Kd, 1.0);
  gemm_nt_mfma_f32<<<gemm_grid, 256, 0, stream>>>(value, Wv, nullptr, Vf);

  attn_flash<<<Bb * Hh * (Ls / 64), 256, 0, stream>>>(Qd, Kd, Vf, attn, Of);
  attn_scale<<<Bb * Hh * Ls, 256, 0, stream>>>(attn, Qd);

  gemm_nt_mfma_f32<<<gemm_grid, 256, 0, stream>>>(Of, Wo, bo, out0);
}

// Round 5
// 4202.821 us; speedup vs baseline: 1.3634x; 1.3634x over previous
//
#include <hip/hip_runtime.h>
#include <math.h>

#define Bb 4
#define Ls 2048
#define Dd 1024
#define Hh 16
#define HDm 64
#define ML (Bb*Ls)   /* 8192 rows */

typedef double f64x4 __attribute__((ext_vector_type(4)));
typedef unsigned int u32;

// HBM -> LDS direct (no VGPR round-trip). LDS dest = wave-uniform base +
// lane*16 (m104); global src is per-lane. size must be literal 16 (m97).
__device__ __forceinline__ void gload16(const void* g, void* l) {
  __builtin_amdgcn_global_load_lds(
      (const __attribute__((address_space(1))) u32*)g,
      (__attribute__((address_space(3))) u32*)l, 16, 0, 0);
}

// ---------------------------------------------------------------------------
// NT GEMM via f64 MFMA: C[m,n] = outscale * sum_k A[m,k]*B[n,k], f64 out.
// A,B f32 staged in LDS, cvt to f64 at fragment load; accumulate in f64
// matrix pipe. Block 256 = 4 waves; tile 64x64.
// MFMA f64 16x16x4 layouts (validated round 2): A row=lane&15, k=lane>>4;
// B col=lane&15, k=lane>>4; D row=4*reg+(lane>>4), col=lane&15.
// fp64 needed: logits sigma~1.1e6; fp32 projections give ~4e3 error -> fail.
// ---------------------------------------------------------------------------
__global__ __launch_bounds__(256) void gemm_nt_mfma_f64(
    const float* __restrict__ A, const float* __restrict__ B,
    double* __restrict__ C, double outscale) {
  const int N = Dd, K = Dd;
  __shared__ float As[64][17];
  __shared__ float Bs[64][17];
  const int tid = threadIdx.x;
  const int lane = tid & 63;
  const int w = tid >> 6;
  const int lrow = lane & 15, lk = lane >> 4;
  const int bm = blockIdx.y * 64, bn = blockIdx.x * 64;
  const int sr = tid >> 4, sc = tid & 15;   // staging coords

  f64x4 acc[4] = {{0.,0.,0.,0.},{0.,0.,0.,0.},{0.,0.,0.,0.},{0.,0.,0.,0.}};

  for (int k0 = 0; k0 < K; k0 += 16) {
#pragma unroll
    for (int i = 0; i < 4; i++) {
      int r = sr + 16 * i;
      As[r][sc] = A[(size_t)(bm + r) * K + k0 + sc];
      Bs[r][sc] = B[(size_t)(bn + r) * K + k0 + sc];
    }
    __syncthreads();
#pragma unroll
    for (int t = 0; t < 4; t++) {
      double a = (double)As[16 * w + lrow][4 * t + lk];
#pragma unroll
      for (int j = 0; j < 4; j++) {
        double bb = (double)Bs[16 * j + lrow][4 * t + lk];
        acc[j] = __builtin_amdgcn_mfma_f64_16x16x4f64(a, bb, acc[j], 0, 0, 0);
      }
    }
    __syncthreads();
  }
#pragma unroll
  for (int j = 0; j < 4; j++)
#pragma unroll
    for (int d = 0; d < 4; d++) {
      size_t m = (size_t)(bm + 16 * w + 4 * d + lk);
      C[m * N + bn + 16 * j + lrow] = acc[j][d] * outscale;
    }
}

// ---------------------------------------------------------------------------
// Same GEMM, f32 output + optional bias (f64 accumulate inside).
// ---------------------------------------------------------------------------
__global__ __launch_bounds__(256) void gemm_nt_mfma_f32(
    const float* __restrict__ A, const float* __restrict__ B,
    const float* __restrict__ bias, float* __restrict__ C) {
  const int N = Dd, K = Dd;
  __shared__ float As[64][17];
  __shared__ float Bs[64][17];
  const int tid = threadIdx.x;
  const int lane = tid & 63;
  const int w = tid >> 6;
  const int lrow = lane & 15, lk = lane >> 4;
  const int bm = blockIdx.y * 64, bn = blockIdx.x * 64;
  const int sr = tid >> 4, sc = tid & 15;

  f64x4 acc[4] = {{0.,0.,0.,0.},{0.,0.,0.,0.},{0.,0.,0.,0.},{0.,0.,0.,0.}};

  for (int k0 = 0; k0 < K; k0 += 16) {
#pragma unroll
    for (int i = 0; i < 4; i++) {
      int r = sr + 16 * i;
      As[r][sc] = A[(size_t)(bm + r) * K + k0 + sc];
      Bs[r][sc] = B[(size_t)(bn + r) * K + k0 + sc];
    }
    __syncthreads();
#pragma unroll
    for (int t = 0; t < 4; t++) {
      double a = (double)As[16 * w + lrow][4 * t + lk];
#pragma unroll
      for (int j = 0; j < 4; j++) {
        double bb = (double)Bs[16 * j + lrow][4 * t + lk];
        acc[j] = __builtin_amdgcn_mfma_f64_16x16x4f64(a, bb, acc[j], 0, 0, 0);
      }
    }
    __syncthreads();
  }
#pragma unroll
  for (int j = 0; j < 4; j++)
#pragma unroll
    for (int d = 0; d < 4; d++) {
      size_t m = (size_t)(bm + 16 * w + 4 * d + lk);
      int n = bn + 16 * j + lrow;
      float v = (float)acc[j][d];
      if (bias) v += bias[n];
      C[m * N + n] = v;
    }
}

// ---------------------------------------------------------------------------
// One-sweep flash attention, v7: double-buffered global_load_lds staging.
// History: v4 (128 VGPR, 2 blk/CU, 1710us) had ~2600 cyc/tile serial staging
// stall. v5 reg-prefetch -> 132 VGPR -> occupancy halved (2828us). v6 forced
// 64 VGPR via launch_bounds(256,4) -> scratch spills, FETCH 426MB->5.6GB
// (3170us). v7 hides staging latency with ZERO VGPRs: K/V staged by
// global_load_lds into double-buffered LDS; one barrier per tile (issue into
// buf^1 at top, compute on buf, __syncthreads drains vmcnt + publishes);
// loads span the whole ~5000cyc compute phase >> ~900cyc HBM latency.
// K LDS is LINEAR [32][64] f64 (global_load_lds writes base+lane*16; padding
// illegal) with XOR swizzle byte^=(row&7)<<4 applied BOTH sides (rule 21):
// write side via pre-swizzled per-lane GLOBAL address, read side via XOR'd
// ds_read_b64 index -> 4 lanes/bank = b64 bandwidth floor (was 16-way).
// V linear [32][64] f32 needs no swizzle (PV read is row-uniform float4 ->
// broadcast/2-way). Softmax numerics bit-identical to v4/v6 (absmax 48).
// LDS: 2*16384 (K) + 2*8192 (V) + 10240 (Ps) = 59392 B -> 2 blocks/CU.
// ---------------------------------------------------------------------------
__global__ __launch_bounds__(256) void attn_flash(
    double* __restrict__ Qd, const double* __restrict__ Kd,
    const float* __restrict__ Vf, float* __restrict__ attn,
    float* __restrict__ O) {
  __shared__ double Kbuf[2][32 * 64];
  __shared__ float  Vbuf[2][32 * 64];
  __shared__ float  Ps[4][32 * 20];   // per-wave P^T: [col 0..31][slot 0..15]

  const int tid = threadIdx.x;
  const int lane = tid & 63;
  const int w = tid >> 6;             // wave 0..3 -> q-row strip 16w
  const int lrow = lane & 15;         // A-row / B,D-col index
  const int lk = lane >> 4;           // k index / D row low bits
  const int blk = blockIdx.x;
  const int qt = blk & 31;            // 32 q-tiles of 64 rows
  const int h = (blk >> 5) & 15;
  const int b = blk >> 9;
  const int l0 = qt * 64;

  const double* Qg = Qd + ((size_t)(b * Ls + l0)) * Dd + h * HDm;
  const double* Kg = Kd + ((size_t)b * Ls) * Dd + h * HDm;
  const float*  Vg = Vf + ((size_t)b * Ls) * Dd + h * HDm;
  float* aout = attn + ((size_t)((b * Hh + h) * Ls + l0)) * Ls;

  // Q fragments: lane holds Q[16w+lrow][4t+lk] for t=0..15 (whole sweep);
  // Qd is pre-scaled by 0.125 at projection time. Loaded BEFORE any stash
  // writes touch these rows.
  double qreg[16];
#pragma unroll
  for (int t = 0; t < 16; t++)
    qreg[t] = Qg[(size_t)(16 * w + lrow) * Dd + 4 * t + lk];

  // staging geometry (per-lane constants)
  const int l16 = (lane & 31) * 16;   // K: 16B block within a 512B row
  const int halfk = lane >> 5;        // K: row parity within 2-row chunk
  const int vin = (lane & 15) * 16;   // V: 16B block within a 256B row
  const int vrow = lane >> 4;         // V: row within 4-row chunk
  const int sx = (lrow & 7) << 1;     // K read swizzle (double-index units)

  // stage one 32-key tile into buffer bsel; wave w owns K chunks {w,w+4,
  // w+8,w+12} and V chunks {w,w+4} (1KB each = 64 lanes * 16B)
  auto stage = [&](int kts, int bsel) {
#pragma unroll
    for (int jj = 0; jj < 4; jj++) {
      int i = w + 4 * jj;
      int row = 2 * i + halfk;
      int inner = l16 ^ ((row & 7) << 4);   // pre-swizzled global source
      const char* g = (const char*)Kg + (((size_t)(kts * 32 + row)) << 13) + inner;
      gload16(g, (char*)(&Kbuf[bsel][0]) + i * 1024);
    }
#pragma unroll
    for (int jj = 0; jj < 2; jj++) {
      int j = w + 4 * jj;
      int row = 4 * j + vrow;
      const char* g = (const char*)Vg + (((size_t)(kts * 32 + row)) << 12) + vin;
      gload16(g, (char*)(&Vbuf[bsel][0]) + j * 1024);
    }
  };

  float mreff[4];
  double sacc[4];
  float Oacc[4][4];
#pragma unroll
  for (int d = 0; d < 4; d++) {
    mreff[d] = -INFINITY;
    sacc[d] = 0.0;
#pragma unroll
    for (int j = 0; j < 4; j++) Oacc[d][j] = 0.0f;
  }

  stage(0, 0);
  __syncthreads();   // drains vmcnt(0): tile 0 resident for all waves

  int cur = 0;
  for (int kt = 0; kt < 64; kt++) {
    if (kt < 63) stage(kt + 1, cur ^ 1);   // async: lands during compute

    const double* Kb = &Kbuf[cur][0];
    const float*  Vb = &Vbuf[cur][0];

    // QK^T: E[r][c] = sum_k Q[r][k] K[c][k]; quadrant 0: keys 0-15, 1: 16-31
    // K read index XOR-swizzled to match the staged layout.
    f64x4 acc0 = {0.0, 0.0, 0.0, 0.0};
    f64x4 acc1 = {0.0, 0.0, 0.0, 0.0};
#pragma unroll
    for (int t = 0; t < 16; t++) {
      int ko = (4 * t + lk) ^ sx;
      double b0 = Kb[lrow * 64 + ko];
      double b1 = Kb[(16 + lrow) * 64 + ko];
      acc0 = __builtin_amdgcn_mfma_f64_16x16x4f64(qreg[t], b0, acc0, 0, 0, 0);
      acc1 = __builtin_amdgcn_mfma_f64_16x16x4f64(qreg[t], b1, acc1, 0, 0, 0);
    }

    // online softmax per owned row: acc[d] is row 4*d + lk (f64 D layout),
    // col lrow (acc0) / 16+lrow (acc1). Logits pre-scaled via Q.
#pragma unroll
    for (int d = 0; d < 4; d++) {
      double e0 = acc0[d];
      double e1 = acc1[d];
      float tmf = fmaxf((float)e0, (float)e1);
#pragma unroll
      for (int m = 1; m < 16; m <<= 1) tmf = fmaxf(tmf, __shfl_xor(tmf, m));
      float mo_f = mreff[d];
      float ref_f = fmaxf(mo_f, tmf);        // float-rounded running ref
      double ref = (double)ref_f;
      float p0 = expf((float)(e0 - ref));
      float p1 = expf((float)(e1 - ref));
      double ts = (double)p0 + (double)p1;
#pragma unroll
      for (int m = 1; m < 16; m <<= 1) ts += __shfl_xor(ts, m);
      float factor = expf(mo_f - ref_f);     // <= 1
      sacc[d] = sacc[d] * (double)factor + ts;
      mreff[d] = ref_f;
#pragma unroll
      for (int j = 0; j < 4; j++) Oacc[d][j] *= factor;
      int row = 16 * w + 4 * d + lk;
      aout[(size_t)row * Ls + kt * 32 + lrow] = p0;
      aout[(size_t)row * Ls + kt * 32 + 16 + lrow] = p1;
      if (lrow == 0) {  // stash per-(row,tile) ref in dead Qd slice
        ((float*)(Qd + ((size_t)(b * Ls + l0 + row)) * Dd + h * HDm))[kt] = ref_f;
      }
      // P^T scalar writes: slot 4*lk+d holds row 4*d+lk of col lrow (/+16)
      Ps[w][lrow * 20 + 4 * lk + d] = p0;
      Ps[w][(16 + lrow) * 20 + 4 * lk + d] = p1;
    }

    // PV: lane owns rows 4*d+lk x dims 4*lrow+j; p broadcast from Ps
    // (reader float4 at 4*lk recovers its own softmax rows 4*d+lk)
#pragma unroll
    for (int t = 0; t < 32; t++) {
      float4 pb = *(const float4*)(&Ps[w][t * 20 + 4 * lk]);
      float4 vv = *(const float4*)(&Vb[t * 64 + lrow * 4]);
      Oacc[0][0] = fmaf(pb.x, vv.x, Oacc[0][0]);
      Oacc[0][1] = fmaf(pb.x, vv.y, Oacc[0][1]);
      Oacc[0][2] = fmaf(pb.x, vv.z, Oacc[0][2]);
      Oacc[0][3] = fmaf(pb.x, vv.w, Oacc[0][3]);
      Oacc[1][0] = fmaf(pb.y, vv.x, Oacc[1][0]);
      Oacc[1][1] = fmaf(pb.y, vv.y, Oacc[1][1]);
      Oacc[1][2] = fmaf(pb.y, vv.z, Oacc[1][2]);
      Oacc[1][3] = fmaf(pb.y, vv.w, Oacc[1][3]);
      Oacc[2][0] = fmaf(pb.z, vv.x, Oacc[2][0]);
      Oacc[2][1] = fmaf(pb.z, vv.y, Oacc[2][1]);
      Oacc[2][2] = fmaf(pb.z, vv.z, Oacc[2][2]);
      Oacc[2][3] = fmaf(pb.z, vv.w, Oacc[2][3]);
      Oacc[3][0] = fmaf(pb.w, vv.x, Oacc[3][0]);
      Oacc[3][1] = fmaf(pb.w, vv.y, Oacc[3][1]);
      Oacc[3][2] = fmaf(pb.w, vv.z, Oacc[3][2]);
      Oacc[3][3] = fmaf(pb.w, vv.w, Oacc[3][3]);
    }

    __syncthreads();  // drains vmcnt (my prefetch landed) + publishes buf^1;
                      // also releases buf[cur] for overwrite next iteration
    cur ^= 1;
  }

  // epilogue: normalize O, stash final ref + sum per row (row = 4*d + lk)
#pragma unroll
  for (int d = 0; d < 4; d++) {
    int row = 16 * w + 4 * d + lk;
    float sv = (float)(1.0 / sacc[d]);
    float4 ov = make_float4(Oacc[d][0] * sv, Oacc[d][1] * sv,
                            Oacc[d][2] * sv, Oacc[d][3] * sv);
    *(float4*)(O + ((size_t)(b * Ls + l0 + row)) * Dd + h * HDm + lrow * 4) = ov;
    if (lrow == 0) {
      float* mrow = (float*)(Qd + ((size_t)(b * Ls + l0 + row)) * Dd + h * HDm);
      mrow[64] = mreff[d];
      *(double*)(mrow + 66) = sacc[d];
    }
  }
}

// ---------------------------------------------------------------------------
// Rescale: p = p~ * exp(ref_t - ref_final) / s. One block per attention row.
// ---------------------------------------------------------------------------
__global__ __launch_bounds__(256) void attn_scale(
    float* __restrict__ attn, const double* __restrict__ Qd) {
  int R = blockIdx.x;                 // 0..131071: ((b*Hh+h)*Ls + l)
  int b = R >> 15;
  int rem = R & 32767;
  int h = rem >> 11;
  int l = rem & 2047;
  const float* mrow = (const float*)(Qd + ((size_t)(b * Ls + l)) * Dd + h * HDm);
  int tid = threadIdx.x;
  int kt = tid >> 2;                  // 8 cols per thread, within one 32-col tile
  double mt = (double)mrow[kt];
  double mf = (double)mrow[64];
  double s = *(const double*)(mrow + 66);
  float sc = (float)(exp(mt - mf) / s);
  float4* ap = (float4*)(attn + (size_t)R * Ls + tid * 8);
  float4 a0 = ap[0], a1 = ap[1];
  a0.x *= sc; a0.y *= sc; a0.z *= sc; a0.w *= sc;
  a1.x *= sc; a1.y *= sc; a1.z *= sc; a1.w *= sc;
  ap[0] = a0; ap[1] = a1;
}

// ---------------------------------------------------------------------------
extern "C" void kernel_launch(void* const* d_in, const int* in_sizes, int n_in,
                              void* d_out, int out_size, void* d_ws, size_t ws_size,
                              hipStream_t stream) {
  const float* query = (const float*)d_in[0];
  const float* key   = (const float*)d_in[1];
  const float* value = (const float*)d_in[2];
  const float* Wq    = (const float*)d_in[3];
  const float* Wk    = (const float*)d_in[4];
  const float* Wv    = (const float*)d_in[5];
  const float* Wo    = (const float*)d_in[6];
  const float* bo    = (const float*)d_in[7];

  float* out0 = (float*)d_out;            // [B,L,D]
  float* attn = out0 + (size_t)ML * Dd;   // [B,H,L,L]

  // ws: Qd (64MB f64) | Kd (64MB f64) | Vf (32MB f32) | Of (32MB f32)
  char* ws = (char*)d_ws;
  double* Qd = (double*)ws;
  double* Kd = (double*)(ws + (size_t)ML * Dd * 8);
  float*  Vf = (float*)(ws + (size_t)ML * Dd * 16);
  float*  Of = (float*)(ws + (size_t)ML * Dd * 16 + (size_t)ML * Dd * 4);

  dim3 gemm_grid(Dd / 64, ML / 64);
  // Q pre-scaled by softmax 1/sqrt(64) = 0.125 (exact pow2 -> logits
  // bit-identical to post-scaling)
  gemm_nt_mfma_f64<<<gemm_grid, 256, 0, stream>>>(query, Wq, Qd, 0.125);
  gemm_nt_mfma_f64<<<gemm_grid, 256, 0, stream>>>(key,   Wk, Kd, 1.0);
  gemm_nt_mfma_f32<<<gemm_grid, 256, 0, stream>>>(value, Wv, nullptr, Vf);

  attn_flash<<<Bb * Hh * (Ls / 64), 256, 0, stream>>>(Qd, Kd, Vf, attn, Of);
  attn_scale<<<Bb * Hh * Ls, 256, 0, stream>>>(attn, Qd);

  gemm_nt_mfma_f32<<<gemm_grid, 256, 0, stream>>>(Of, Wo, bo, out0);
}

// Round 6
// 3971.740 us; speedup vs baseline: 1.4427x; 1.0582x over previous
//
#include <hip/hip_runtime.h>
#include <math.h>

#define Bb 4
#define Ls 2048
#define Dd 1024
#define Hh 16
#define HDm 64
#define ML (Bb*Ls)   /* 8192 rows */

typedef double f64x4 __attribute__((ext_vector_type(4)));
typedef float  f32x4 __attribute__((ext_vector_type(4)));
typedef short  bf16x8 __attribute__((ext_vector_type(8)));
typedef unsigned int u32;
typedef unsigned short u16;

// HBM -> LDS direct (no VGPR round-trip). LDS dest = wave-uniform base +
// lane*16 (m104); global src is per-lane. size must be literal 16 (m97).
__device__ __forceinline__ void gload16(const void* g, void* l) {
  __builtin_amdgcn_global_load_lds(
      (const __attribute__((address_space(1))) u32*)g,
      (__attribute__((address_space(3))) u32*)l, 16, 0, 0);
}

// f32 -> bf16, round-to-nearest-even (finite inputs only)
__device__ __forceinline__ u16 f2bf(float f) {
  u32 u = __float_as_uint(f);
  u += 0x7FFFu + ((u >> 16) & 1u);
  return (u16)(u >> 16);
}

// ---------------------------------------------------------------------------
// NT GEMM via f64 MFMA: C[m,n] = outscale * sum_k A[m,k]*B[n,k], f64 out.
// MFMA f64 16x16x4 layouts (validated round 2): A row=lane&15, k=lane>>4;
// B col=lane&15, k=lane>>4; D row=4*reg+(lane>>4), col=lane&15.
// fp64 needed: logits sigma~1.1e6; fp32 projections give ~4e3 error -> fail.
// ---------------------------------------------------------------------------
__global__ __launch_bounds__(256) void gemm_nt_mfma_f64(
    const float* __restrict__ A, const float* __restrict__ B,
    double* __restrict__ C, double outscale) {
  const int N = Dd, K = Dd;
  __shared__ float As[64][17];
  __shared__ float Bs[64][17];
  const int tid = threadIdx.x;
  const int lane = tid & 63;
  const int w = tid >> 6;
  const int lrow = lane & 15, lk = lane >> 4;
  const int bm = blockIdx.y * 64, bn = blockIdx.x * 64;
  const int sr = tid >> 4, sc = tid & 15;   // staging coords

  f64x4 acc[4] = {{0.,0.,0.,0.},{0.,0.,0.,0.},{0.,0.,0.,0.},{0.,0.,0.,0.}};

  for (int k0 = 0; k0 < K; k0 += 16) {
#pragma unroll
    for (int i = 0; i < 4; i++) {
      int r = sr + 16 * i;
      As[r][sc] = A[(size_t)(bm + r) * K + k0 + sc];
      Bs[r][sc] = B[(size_t)(bn + r) * K + k0 + sc];
    }
    __syncthreads();
#pragma unroll
    for (int t = 0; t < 4; t++) {
      double a = (double)As[16 * w + lrow][4 * t + lk];
#pragma unroll
      for (int j = 0; j < 4; j++) {
        double bb = (double)Bs[16 * j + lrow][4 * t + lk];
        acc[j] = __builtin_amdgcn_mfma_f64_16x16x4f64(a, bb, acc[j], 0, 0, 0);
      }
    }
    __syncthreads();
  }
#pragma unroll
  for (int j = 0; j < 4; j++)
#pragma unroll
    for (int d = 0; d < 4; d++) {
      size_t m = (size_t)(bm + 16 * w + 4 * d + lk);
      C[m * N + bn + 16 * j + lrow] = acc[j][d] * outscale;
    }
}

// ---------------------------------------------------------------------------
// Same GEMM, f32 output + optional bias (f64 accumulate inside).
// ---------------------------------------------------------------------------
__global__ __launch_bounds__(256) void gemm_nt_mfma_f32(
    const float* __restrict__ A, const float* __restrict__ B,
    const float* __restrict__ bias, float* __restrict__ C) {
  const int N = Dd, K = Dd;
  __shared__ float As[64][17];
  __shared__ float Bs[64][17];
  const int tid = threadIdx.x;
  const int lane = tid & 63;
  const int w = tid >> 6;
  const int lrow = lane & 15, lk = lane >> 4;
  const int bm = blockIdx.y * 64, bn = blockIdx.x * 64;
  const int sr = tid >> 4, sc = tid & 15;

  f64x4 acc[4] = {{0.,0.,0.,0.},{0.,0.,0.,0.},{0.,0.,0.,0.},{0.,0.,0.,0.}};

  for (int k0 = 0; k0 < K; k0 += 16) {
#pragma unroll
    for (int i = 0; i < 4; i++) {
      int r = sr + 16 * i;
      As[r][sc] = A[(size_t)(bm + r) * K + k0 + sc];
      Bs[r][sc] = B[(size_t)(bn + r) * K + k0 + sc];
    }
    __syncthreads();
#pragma unroll
    for (int t = 0; t < 4; t++) {
      double a = (double)As[16 * w + lrow][4 * t + lk];
#pragma unroll
      for (int j = 0; j < 4; j++) {
        double bb = (double)Bs[16 * j + lrow][4 * t + lk];
        acc[j] = __builtin_amdgcn_mfma_f64_16x16x4f64(a, bb, acc[j], 0, 0, 0);
      }
    }
    __syncthreads();
  }
#pragma unroll
  for (int j = 0; j < 4; j++)
#pragma unroll
    for (int d = 0; d < 4; d++) {
      size_t m = (size_t)(bm + 16 * w + 4 * d + lk);
      int n = bn + 16 * j + lrow;
      float v = (float)acc[j][d];
      if (bias) v += bias[n];
      C[m * N + n] = v;
    }
}

// ---------------------------------------------------------------------------
// Same GEMM, bf16 output (for V: PV now runs on bf16 MFMA; one rounding,
// applied at projection time; f64 accumulate kept).
// ---------------------------------------------------------------------------
__global__ __launch_bounds__(256) void gemm_nt_mfma_bf16o(
    const float* __restrict__ A, const float* __restrict__ B,
    u16* __restrict__ C) {
  const int N = Dd, K = Dd;
  __shared__ float As[64][17];
  __shared__ float Bs[64][17];
  const int tid = threadIdx.x;
  const int lane = tid & 63;
  const int w = tid >> 6;
  const int lrow = lane & 15, lk = lane >> 4;
  const int bm = blockIdx.y * 64, bn = blockIdx.x * 64;
  const int sr = tid >> 4, sc = tid & 15;

  f64x4 acc[4] = {{0.,0.,0.,0.},{0.,0.,0.,0.},{0.,0.,0.,0.},{0.,0.,0.,0.}};

  for (int k0 = 0; k0 < K; k0 += 16) {
#pragma unroll
    for (int i = 0; i < 4; i++) {
      int r = sr + 16 * i;
      As[r][sc] = A[(size_t)(bm + r) * K + k0 + sc];
      Bs[r][sc] = B[(size_t)(bn + r) * K + k0 + sc];
    }
    __syncthreads();
#pragma unroll
    for (int t = 0; t < 4; t++) {
      double a = (double)As[16 * w + lrow][4 * t + lk];
#pragma unroll
      for (int j = 0; j < 4; j++) {
        double bb = (double)Bs[16 * j + lrow][4 * t + lk];
        acc[j] = __builtin_amdgcn_mfma_f64_16x16x4f64(a, bb, acc[j], 0, 0, 0);
      }
    }
    __syncthreads();
  }
#pragma unroll
  for (int j = 0; j < 4; j++)
#pragma unroll
    for (int d = 0; d < 4; d++) {
      size_t m = (size_t)(bm + 16 * w + 4 * d + lk);
      C[m * N + bn + 16 * j + lrow] = f2bf((float)acc[j][d]);
    }
}

// ---------------------------------------------------------------------------
// One-sweep flash attention, v8: PV on the matrix pipe.
// v7 (1650us): wall ~7700cyc/wave-tile vs MFMA 2235 + VALU 2985 busy; VALU
// half-filled by 512 scalar PV fmafs/tile; only 2 blocks/CU (LDS 59392).
// v8: PV = mfma_f32_16x16x32_bf16: A = P bf16 (via per-wave LDS tile Pb,
// transposing the f64-D layout to A layout row=lane&15,k=8*(lane>>4)+j),
// B = V bf16 (linear [32][64] LDS, 8 scalar u16 reads/frag). 4 MFMA replace
// 512 fmafs (-1000 VALU cyc/tile) and the 64 b128 Ps/Vs reads (-750 LDS).
// PV D layout row=4*(lane>>4)+reg differs from f64-D's 4d+lk -> per-row
// rescale factor & 1/s cross layouts via 16-float Fs broadcast (wave-
// internal LDS ordering, same mechanism as the 3x-validated Ps pattern).
// V is bf16 in GLOBAL (projection writes bf16) -> staging 1 gload16/wave.
// Q/K/softmax path BIT-IDENTICAL to v7 (absmax 48); bf16 P/V rounding adds
// ~sigma 6 to out0 vs slack 112.6-48.
// LDS: Kbuf 32768 + Vb 8192 + Pb 4096 + Fs 256 = 45312 -> 3 blocks/CU.
// ---------------------------------------------------------------------------
__global__ __launch_bounds__(256) void attn_flash(
    double* __restrict__ Qd, const double* __restrict__ Kd,
    const u16* __restrict__ Vf, float* __restrict__ attn,
    float* __restrict__ O) {
  __shared__ __align__(16) double Kbuf[2][32 * 64];
  __shared__ __align__(16) u16    Vb16[2][32 * 64];  // [key][dim] bf16
  __shared__ __align__(16) u16    Pb[4][16 * 32];    // per-wave [row][key] bf16
  __shared__ __align__(16) float  Fs[4][16];         // per-wave per-row scalar

  const int tid = threadIdx.x;
  const int lane = tid & 63;
  const int w = tid >> 6;             // wave 0..3 -> q-row strip 16w
  const int lrow = lane & 15;         // A-row / B,D-col index
  const int lk = lane >> 4;           // k-group index / D row bits
  const int blk = blockIdx.x;
  const int qt = blk & 31;            // 32 q-tiles of 64 rows
  const int h = (blk >> 5) & 15;      // head
  const int b = blk >> 9;
  const int l0 = qt * 64;

  const double* Qg = Qd + ((size_t)(b * Ls + l0)) * Dd + h * HDm;
  const double* Kg = Kd + ((size_t)b * Ls) * Dd + h * HDm;
  const u16*    Vg = Vf + ((size_t)b * Ls) * Dd + h * HDm;
  float* aout = attn + ((size_t)((b * Hh + h) * Ls + l0)) * Ls;

  // Q fragments: lane holds Q[16w+lrow][4t+lk] for t=0..15 (whole sweep);
  // Qd is pre-scaled by 0.125 at projection time.
  double qreg[16];
#pragma unroll
  for (int t = 0; t < 16; t++)
    qreg[t] = Qg[(size_t)(16 * w + lrow) * Dd + 4 * t + lk];

  // K staging geometry (v7, validated): linear [32][64] f64 with XOR swizzle
  // byte^=(row&7)<<4 on BOTH sides (pre-swizzled global src + XOR'd read).
  const int l16 = (lane & 31) * 16;
  const int halfk = lane >> 5;
  const int sx = (lrow & 7) << 1;     // K read swizzle (element units)

  auto stage = [&](int kts, int bsel) {
#pragma unroll
    for (int jj = 0; jj < 4; jj++) {
      int i = w + 4 * jj;
      int row = 2 * i + halfk;
      int inner = l16 ^ ((row & 7) << 4);   // pre-swizzled global source
      const char* g = (const char*)Kg + (((size_t)(kts * 32 + row)) << 13) + inner;
      gload16(g, (char*)(&Kbuf[bsel][0]) + i * 1024);
    }
    // V: wave w stages keys 8w..8w+7 bf16 (1KB); lane: key 8w+(lane>>3),
    // dims 8*(lane&7).. -> LDS linear [key][64] bf16
    {
      const char* g = (const char*)Vg +
          ((size_t)(kts * 32 + 8 * w + (lane >> 3))) * (Dd * 2) + (lane & 7) * 16;
      gload16(g, (char*)(&Vb16[bsel][0]) + w * 1024);
    }
  };

  float mreff[4];
  double sacc[4];
  f32x4 pacc[4];   // PV accum per dim-quadrant; D: col=lrow, row=4*lk+reg
#pragma unroll
  for (int d = 0; d < 4; d++) {
    mreff[d] = -INFINITY;
    sacc[d] = 0.0;
    pacc[d] = (f32x4){0.f, 0.f, 0.f, 0.f};
  }

  stage(0, 0);
  __syncthreads();   // drains vmcnt(0): tile 0 resident for all waves

  int cur = 0;
  for (int kt = 0; kt < 64; kt++) {
    if (kt < 63) stage(kt + 1, cur ^ 1);   // async: lands during compute

    const double* Kb = &Kbuf[cur][0];

    // QK^T: E[r][c] = sum_k Q[r][k] K[c][k]; quadrant 0: keys 0-15, 1: 16-31
    f64x4 acc0 = {0.0, 0.0, 0.0, 0.0};
    f64x4 acc1 = {0.0, 0.0, 0.0, 0.0};
#pragma unroll
    for (int t = 0; t < 16; t++) {
      int ko = (4 * t + lk) ^ sx;
      double b0 = Kb[lrow * 64 + ko];
      double b1 = Kb[(16 + lrow) * 64 + ko];
      acc0 = __builtin_amdgcn_mfma_f64_16x16x4f64(qreg[t], b0, acc0, 0, 0, 0);
      acc1 = __builtin_amdgcn_mfma_f64_16x16x4f64(qreg[t], b1, acc1, 0, 0, 0);
    }

    // online softmax per owned row: acc[d] is row 4*d + lk (f64 D layout),
    // col lrow (acc0) / 16+lrow (acc1). Logits pre-scaled via Q.
#pragma unroll
    for (int d = 0; d < 4; d++) {
      double e0 = acc0[d];
      double e1 = acc1[d];
      float tmf = fmaxf((float)e0, (float)e1);
#pragma unroll
      for (int m = 1; m < 16; m <<= 1) tmf = fmaxf(tmf, __shfl_xor(tmf, m));
      float mo_f = mreff[d];
      float ref_f = fmaxf(mo_f, tmf);        // float-rounded running ref
      double ref = (double)ref_f;
      float p0 = expf((float)(e0 - ref));
      float p1 = expf((float)(e1 - ref));
      double ts = (double)p0 + (double)p1;
#pragma unroll
      for (int m = 1; m < 16; m <<= 1) ts += __shfl_xor(ts, m);
      float factor = expf(mo_f - ref_f);     // <= 1
      sacc[d] = sacc[d] * (double)factor + ts;
      mreff[d] = ref_f;
      int row = 16 * w + 4 * d + lk;
      aout[(size_t)row * Ls + kt * 32 + lrow] = p0;
      aout[(size_t)row * Ls + kt * 32 + 16 + lrow] = p1;
      if (lrow == 0) {  // stash per-(row,tile) ref; publish rescale factor
        ((float*)(Qd + ((size_t)(b * Ls + l0 + row)) * Dd + h * HDm))[kt] = ref_f;
        Fs[w][4 * d + lk] = factor;
      }
      // P tile in A-operand layout: Pb[row 4d+lk][key] bf16
      Pb[w][(4 * d + lk) * 32 + lrow] = f2bf(p0);
      Pb[w][(4 * d + lk) * 32 + 16 + lrow] = f2bf(p1);
    }

    // PV on matrix pipe (wave-internal LDS order: reads see writes above).
    // A frag: P[row=lrow][k=8*lk+j] = one b128 from Pb.
    bf16x8 afr = *(const bf16x8*)&Pb[w][lrow * 32 + 8 * lk];
    f32x4 fv = *(const f32x4*)&Fs[w][4 * lk];   // factors for rows 4lk+0..3
    const u16* Vb = &Vb16[cur][0];
#pragma unroll
    for (int q = 0; q < 4; q++) {
      pacc[q][0] *= fv[0];
      pacc[q][1] *= fv[1];
      pacc[q][2] *= fv[2];
      pacc[q][3] *= fv[3];
      bf16x8 bfr;  // B frag: V[k=8*lk+r][col=16q+lrow]
#pragma unroll
      for (int r = 0; r < 8; r++)
        bfr[r] = (short)Vb[(8 * lk + r) * 64 + 16 * q + lrow];
      pacc[q] = __builtin_amdgcn_mfma_f32_16x16x32_bf16(afr, bfr, pacc[q], 0, 0, 0);
    }

    __syncthreads();  // drains vmcnt (prefetch landed) + publishes buf^1;
                      // also releases buf[cur] for overwrite next iteration
    cur ^= 1;
  }

  // epilogue: publish 1/s per row (rows 4d+lk), read per PV layout (4lk+r)
  if (lrow == 0) {
#pragma unroll
    for (int d = 0; d < 4; d++) Fs[w][4 * d + lk] = (float)(1.0 / sacc[d]);
  }
  f32x4 sv = *(const f32x4*)&Fs[w][4 * lk];
#pragma unroll
  for (int q = 0; q < 4; q++)
#pragma unroll
    for (int r = 0; r < 4; r++) {
      int row = 16 * w + 4 * lk + r;
      O[((size_t)(b * Ls + l0 + row)) * Dd + h * HDm + 16 * q + lrow] =
          pacc[q][r] * sv[r];
    }
  // stash final ref + sum per row (rows 4d+lk, writers lrow==0)
  if (lrow == 0) {
#pragma unroll
    for (int d = 0; d < 4; d++) {
      int row = 16 * w + 4 * d + lk;
      float* mrow = (float*)(Qd + ((size_t)(b * Ls + l0 + row)) * Dd + h * HDm);
      mrow[64] = mreff[d];
      *(double*)(mrow + 66) = sacc[d];
    }
  }
}

// ---------------------------------------------------------------------------
// Rescale: p = p~ * exp(ref_t - ref_final) / s. One block per attention row.
// ---------------------------------------------------------------------------
__global__ __launch_bounds__(256) void attn_scale(
    float* __restrict__ attn, const double* __restrict__ Qd) {
  int R = blockIdx.x;                 // 0..131071: ((b*Hh+h)*Ls + l)
  int b = R >> 15;
  int rem = R & 32767;
  int h = rem >> 11;
  int l = rem & 2047;
  const float* mrow = (const float*)(Qd + ((size_t)(b * Ls + l)) * Dd + h * HDm);
  int tid = threadIdx.x;
  int kt = tid >> 2;                  // 8 cols per thread, within one 32-col tile
  double mt = (double)mrow[kt];
  double mf = (double)mrow[64];
  double s = *(const double*)(mrow + 66);
  float sc = (float)(exp(mt - mf) / s);
  float4* ap = (float4*)(attn + (size_t)R * Ls + tid * 8);
  float4 a0 = ap[0], a1 = ap[1];
  a0.x *= sc; a0.y *= sc; a0.z *= sc; a0.w *= sc;
  a1.x *= sc; a1.y *= sc; a1.z *= sc; a1.w *= sc;
  ap[0] = a0; ap[1] = a1;
}

// ---------------------------------------------------------------------------
extern "C" void kernel_launch(void* const* d_in, const int* in_sizes, int n_in,
                              void* d_out, int out_size, void* d_ws, size_t ws_size,
                              hipStream_t stream) {
  const float* query = (const float*)d_in[0];
  const float* key   = (const float*)d_in[1];
  const float* value = (const float*)d_in[2];
  const float* Wq    = (const float*)d_in[3];
  const float* Wk    = (const float*)d_in[4];
  const float* Wv    = (const float*)d_in[5];
  const float* Wo    = (const float*)d_in[6];
  const float* bo    = (const float*)d_in[7];

  float* out0 = (float*)d_out;            // [B,L,D]
  float* attn = out0 + (size_t)ML * Dd;   // [B,H,L,L]

  // ws: Qd (64MB f64) | Kd (64MB f64) | Vfb (16MB bf16) | Of (32MB f32)
  char* ws = (char*)d_ws;
  double* Qd  = (double*)ws;
  double* Kd  = (double*)(ws + (size_t)ML * Dd * 8);
  u16*    Vfb = (u16*)(ws + (size_t)ML * Dd * 16);
  float*  Of  = (float*)(ws + (size_t)ML * Dd * 16 + (size_t)ML * Dd * 2);

  dim3 gemm_grid(Dd / 64, ML / 64);
  // Q pre-scaled by softmax 1/sqrt(64) = 0.125 (exact pow2 -> logits
  // bit-identical to post-scaling)
  gemm_nt_mfma_f64<<<gemm_grid, 256, 0, stream>>>(query, Wq, Qd, 0.125);
  gemm_nt_mfma_f64<<<gemm_grid, 256, 0, stream>>>(key,   Wk, Kd, 1.0);
  gemm_nt_mfma_bf16o<<<gemm_grid, 256, 0, stream>>>(value, Wv, Vfb);

  attn_flash<<<Bb * Hh * (Ls / 64), 256, 0, stream>>>(Qd, Kd, Vfb, attn, Of);
  attn_scale<<<Bb * Hh * Ls, 256, 0, stream>>>(attn, Qd);

  gemm_nt_mfma_f32<<<gemm_grid, 256, 0, stream>>>(Of, Wo, bo, out0);
}

// Round 8
// 3968.777 us; speedup vs baseline: 1.4438x; 1.0007x over previous
//
#include <hip/hip_runtime.h>
#include <math.h>

#define Bb 4
#define Ls 2048
#define Dd 1024
#define Hh 16
#define HDm 64
#define ML (Bb*Ls)   /* 8192 rows */

typedef double f64x4 __attribute__((ext_vector_type(4)));
typedef float  f32x4 __attribute__((ext_vector_type(4)));
typedef short  bf16x8 __attribute__((ext_vector_type(8)));
typedef unsigned int u32;
typedef unsigned short u16;

// HBM -> LDS direct (no VGPR round-trip). LDS dest = wave-uniform base +
// lane*16 (m104); global src is per-lane. size must be literal 16 (m97).
__device__ __forceinline__ void gload16(const void* g, void* l) {
  __builtin_amdgcn_global_load_lds(
      (const __attribute__((address_space(1))) u32*)g,
      (__attribute__((address_space(3))) u32*)l, 16, 0, 0);
}

// f32 -> bf16, round-to-nearest-even (finite inputs only)
__device__ __forceinline__ u16 f2bf(float f) {
  u32 u = __float_as_uint(f);
  u += 0x7FFFu + ((u >> 16) & 1u);
  return (u16)(u >> 16);
}

// ---------------------------------------------------------------------------
// Shared NT GEMM core via f64 MFMA, v2: double-buffered global_load_lds
// staging (v7-attn mechanism). v1 had load->waitcnt->write->barrier serial
// each k-step: ~500cyc HBM latency on the critical path -> 565us vs 219us
// MFMA floor (39% util). v2: stage tile k+1 into buf^1 while computing buf,
// ONE barrier per k-step; staging = 1 A + 1 B gload16 per thread.
// LDS tiles LINEAR [64][16] f32 (no padding possible with gload_lds);
// bank fix per rule 21: 16B-block XOR swizzle blk^=(r>>1)&3 applied BOTH
// sides (inverse-permuted per-lane global src + XOR'd read index) ->
// read pattern lands 2 lanes/bank (free, m136).
// MFMA f64 16x16x4 layouts (validated round 2): A row=lane&15, k=lane>>4;
// B col=lane&15, k=lane>>4; D row=4*reg+(lane>>4), col=lane&15.
// Values/order bit-identical to v1 -> absmax unchanged.
// fp64 needed: logits sigma~1.1e6; fp32 projections give ~4e3 error -> fail.
// (round 7: local tile ptrs renamed Abuf/Bbuf -- `Bb` is the batch macro!)
// ---------------------------------------------------------------------------
__device__ __forceinline__ void gemm_core_nt(
    const float* __restrict__ A, const float* __restrict__ B,
    int bm, int bn, int w, int lrow, int lk, f64x4 acc[4]) {
  const int K = Dd;
  __shared__ __align__(16) float As[2][64 * 16];
  __shared__ __align__(16) float Bs[2][64 * 16];
  const int tid = threadIdx.x;
  const int r = tid >> 2, blk = tid & 3;       // staging coords (per-lane)
  const int sblk = blk ^ ((r >> 1) & 3);       // write-side swizzle
  const int sxw = ((lrow >> 1) & 3) << 2;      // read-side swizzle (involution)
  const float* ga = A + (size_t)(bm + r) * K + 4 * sblk;
  const float* gb = B + (size_t)(bn + r) * K + 4 * sblk;

#pragma unroll
  for (int j = 0; j < 4; j++) acc[j] = (f64x4){0., 0., 0., 0.};

  // wave-uniform LDS bases (HW adds lane*16)
  char* la0 = (char*)&As[0][0] + w * 1024;
  char* lb0 = (char*)&Bs[0][0] + w * 1024;
  char* la1 = (char*)&As[1][0] + w * 1024;
  char* lb1 = (char*)&Bs[1][0] + w * 1024;

  gload16(ga, la0);
  gload16(gb, lb0);
  __syncthreads();   // drains vmcnt: tile 0 resident

  int cur = 0;
  for (int k0 = 16; k0 <= K; k0 += 16) {
    if (k0 < K) {                       // prefetch tile k0 into buf^1
      gload16(ga + k0, cur ? la0 : la1);
      gload16(gb + k0, cur ? lb0 : lb1);
    }
    const float* Abuf = &As[cur][0];
    const float* Bbuf = &Bs[cur][0];
#pragma unroll
    for (int t = 0; t < 4; t++) {
      double a = (double)Abuf[(16 * w + lrow) * 16 + ((4 * t + lk) ^ sxw)];
#pragma unroll
      for (int j = 0; j < 4; j++) {
        double bv = (double)Bbuf[(16 * j + lrow) * 16 + ((4 * t + lk) ^ sxw)];
        acc[j] = __builtin_amdgcn_mfma_f64_16x16x4f64(a, bv, acc[j], 0, 0, 0);
      }
    }
    __syncthreads();  // drains vmcnt (prefetch landed) + releases buf[cur]
    cur ^= 1;
  }
}

__global__ __launch_bounds__(256) void gemm_nt_mfma_f64(
    const float* __restrict__ A, const float* __restrict__ B,
    double* __restrict__ C, double outscale) {
  const int tid = threadIdx.x;
  const int lane = tid & 63;
  const int w = tid >> 6;
  const int lrow = lane & 15, lk = lane >> 4;
  const int bm = blockIdx.y * 64, bn = blockIdx.x * 64;
  f64x4 acc[4];
  gemm_core_nt(A, B, bm, bn, w, lrow, lk, acc);
#pragma unroll
  for (int j = 0; j < 4; j++)
#pragma unroll
    for (int d = 0; d < 4; d++) {
      size_t m = (size_t)(bm + 16 * w + 4 * d + lk);
      C[m * Dd + bn + 16 * j + lrow] = acc[j][d] * outscale;
    }
}

__global__ __launch_bounds__(256) void gemm_nt_mfma_f32(
    const float* __restrict__ A, const float* __restrict__ B,
    const float* __restrict__ bias, float* __restrict__ C) {
  const int tid = threadIdx.x;
  const int lane = tid & 63;
  const int w = tid >> 6;
  const int lrow = lane & 15, lk = lane >> 4;
  const int bm = blockIdx.y * 64, bn = blockIdx.x * 64;
  f64x4 acc[4];
  gemm_core_nt(A, B, bm, bn, w, lrow, lk, acc);
#pragma unroll
  for (int j = 0; j < 4; j++)
#pragma unroll
    for (int d = 0; d < 4; d++) {
      size_t m = (size_t)(bm + 16 * w + 4 * d + lk);
      int n = bn + 16 * j + lrow;
      float v = (float)acc[j][d];
      if (bias) v += bias[n];
      C[m * Dd + n] = v;
    }
}

__global__ __launch_bounds__(256) void gemm_nt_mfma_bf16o(
    const float* __restrict__ A, const float* __restrict__ B,
    u16* __restrict__ C) {
  const int tid = threadIdx.x;
  const int lane = tid & 63;
  const int w = tid >> 6;
  const int lrow = lane & 15, lk = lane >> 4;
  const int bm = blockIdx.y * 64, bn = blockIdx.x * 64;
  f64x4 acc[4];
  gemm_core_nt(A, B, bm, bn, w, lrow, lk, acc);
#pragma unroll
  for (int j = 0; j < 4; j++)
#pragma unroll
    for (int d = 0; d < 4; d++) {
      size_t m = (size_t)(bm + 16 * w + 4 * d + lk);
      C[m * Dd + bn + 16 * j + lrow] = f2bf((float)acc[j][d]);
    }
}

// ---------------------------------------------------------------------------
// One-sweep flash attention, v8 (UNCHANGED from round 6 pass, 1380us):
// PV on bf16 matrix pipe; K/V double-buffered global_load_lds; Q in regs;
// softmax f64-MFMA-D-layout rows 4d+lk; Fs crosses f64-D <-> bf16-D layouts.
// LDS: Kbuf 32768 + Vb 8192 + Pb 4096 + Fs 256 = 45312 -> 3 blocks/CU.
// ---------------------------------------------------------------------------
__global__ __launch_bounds__(256) void attn_flash(
    double* __restrict__ Qd, const double* __restrict__ Kd,
    const u16* __restrict__ Vf, float* __restrict__ attn,
    float* __restrict__ O) {
  __shared__ __align__(16) double Kbuf[2][32 * 64];
  __shared__ __align__(16) u16    Vb16[2][32 * 64];  // [key][dim] bf16
  __shared__ __align__(16) u16    Pb[4][16 * 32];    // per-wave [row][key] bf16
  __shared__ __align__(16) float  Fs[4][16];         // per-wave per-row scalar

  const int tid = threadIdx.x;
  const int lane = tid & 63;
  const int w = tid >> 6;             // wave 0..3 -> q-row strip 16w
  const int lrow = lane & 15;         // A-row / B,D-col index
  const int lk = lane >> 4;           // k-group index / D row bits
  const int blk = blockIdx.x;
  const int qt = blk & 31;            // 32 q-tiles of 64 rows
  const int h = (blk >> 5) & 15;      // head
  const int b = blk >> 9;
  const int l0 = qt * 64;

  const double* Qg = Qd + ((size_t)(b * Ls + l0)) * Dd + h * HDm;
  const double* Kg = Kd + ((size_t)b * Ls) * Dd + h * HDm;
  const u16*    Vg = Vf + ((size_t)b * Ls) * Dd + h * HDm;
  float* aout = attn + ((size_t)((b * Hh + h) * Ls + l0)) * Ls;

  // Q fragments: lane holds Q[16w+lrow][4t+lk] for t=0..15 (whole sweep);
  // Qd is pre-scaled by 0.125 at projection time.
  double qreg[16];
#pragma unroll
  for (int t = 0; t < 16; t++)
    qreg[t] = Qg[(size_t)(16 * w + lrow) * Dd + 4 * t + lk];

  // K staging geometry (v7, validated): linear [32][64] f64 with XOR swizzle
  // byte^=(row&7)<<4 on BOTH sides (pre-swizzled global src + XOR'd read).
  const int l16 = (lane & 31) * 16;
  const int halfk = lane >> 5;
  const int sx = (lrow & 7) << 1;     // K read swizzle (element units)

  auto stage = [&](int kts, int bsel) {
#pragma unroll
    for (int jj = 0; jj < 4; jj++) {
      int i = w + 4 * jj;
      int row = 2 * i + halfk;
      int inner = l16 ^ ((row & 7) << 4);   // pre-swizzled global source
      const char* g = (const char*)Kg + (((size_t)(kts * 32 + row)) << 13) + inner;
      gload16(g, (char*)(&Kbuf[bsel][0]) + i * 1024);
    }
    // V: wave w stages keys 8w..8w+7 bf16 (1KB); lane: key 8w+(lane>>3),
    // dims 8*(lane&7).. -> LDS linear [key][64] bf16
    {
      const char* g = (const char*)Vg +
          ((size_t)(kts * 32 + 8 * w + (lane >> 3))) * (Dd * 2) + (lane & 7) * 16;
      gload16(g, (char*)(&Vb16[bsel][0]) + w * 1024);
    }
  };

  float mreff[4];
  double sacc[4];
  f32x4 pacc[4];   // PV accum per dim-quadrant; D: col=lrow, row=4*lk+reg
#pragma unroll
  for (int d = 0; d < 4; d++) {
    mreff[d] = -INFINITY;
    sacc[d] = 0.0;
    pacc[d] = (f32x4){0.f, 0.f, 0.f, 0.f};
  }

  stage(0, 0);
  __syncthreads();   // drains vmcnt(0): tile 0 resident for all waves

  int cur = 0;
  for (int kt = 0; kt < 64; kt++) {
    if (kt < 63) stage(kt + 1, cur ^ 1);   // async: lands during compute

    const double* Kb = &Kbuf[cur][0];

    // QK^T: E[r][c] = sum_k Q[r][k] K[c][k]; quadrant 0: keys 0-15, 1: 16-31
    f64x4 acc0 = {0.0, 0.0, 0.0, 0.0};
    f64x4 acc1 = {0.0, 0.0, 0.0, 0.0};
#pragma unroll
    for (int t = 0; t < 16; t++) {
      int ko = (4 * t + lk) ^ sx;
      double b0 = Kb[lrow * 64 + ko];
      double b1 = Kb[(16 + lrow) * 64 + ko];
      acc0 = __builtin_amdgcn_mfma_f64_16x16x4f64(qreg[t], b0, acc0, 0, 0, 0);
      acc1 = __builtin_amdgcn_mfma_f64_16x16x4f64(qreg[t], b1, acc1, 0, 0, 0);
    }

    // online softmax per owned row: acc[d] is row 4*d + lk (f64 D layout),
    // col lrow (acc0) / 16+lrow (acc1). Logits pre-scaled via Q.
#pragma unroll
    for (int d = 0; d < 4; d++) {
      double e0 = acc0[d];
      double e1 = acc1[d];
      float tmf = fmaxf((float)e0, (float)e1);
#pragma unroll
      for (int m = 1; m < 16; m <<= 1) tmf = fmaxf(tmf, __shfl_xor(tmf, m));
      float mo_f = mreff[d];
      float ref_f = fmaxf(mo_f, tmf);        // float-rounded running ref
      double ref = (double)ref_f;
      float p0 = expf((float)(e0 - ref));
      float p1 = expf((float)(e1 - ref));
      double ts = (double)p0 + (double)p1;
#pragma unroll
      for (int m = 1; m < 16; m <<= 1) ts += __shfl_xor(ts, m);
      float factor = expf(mo_f - ref_f);     // <= 1
      sacc[d] = sacc[d] * (double)factor + ts;
      mreff[d] = ref_f;
      int row = 16 * w + 4 * d + lk;
      aout[(size_t)row * Ls + kt * 32 + lrow] = p0;
      aout[(size_t)row * Ls + kt * 32 + 16 + lrow] = p1;
      if (lrow == 0) {  // stash per-(row,tile) ref; publish rescale factor
        ((float*)(Qd + ((size_t)(b * Ls + l0 + row)) * Dd + h * HDm))[kt] = ref_f;
        Fs[w][4 * d + lk] = factor;
      }
      // P tile in A-operand layout: Pb[row 4d+lk][key] bf16
      Pb[w][(4 * d + lk) * 32 + lrow] = f2bf(p0);
      Pb[w][(4 * d + lk) * 32 + 16 + lrow] = f2bf(p1);
    }

    // PV on matrix pipe (wave-internal LDS order: reads see writes above).
    // A frag: P[row=lrow][k=8*lk+j] = one b128 from Pb.
    bf16x8 afr = *(const bf16x8*)&Pb[w][lrow * 32 + 8 * lk];
    f32x4 fv = *(const f32x4*)&Fs[w][4 * lk];   // factors for rows 4lk+0..3
    const u16* Vb = &Vb16[cur][0];
#pragma unroll
    for (int q = 0; q < 4; q++) {
      pacc[q][0] *= fv[0];
      pacc[q][1] *= fv[1];
      pacc[q][2] *= fv[2];
      pacc[q][3] *= fv[3];
      bf16x8 bfr;  // B frag: V[k=8*lk+r][col=16q+lrow]
#pragma unroll
      for (int r = 0; r < 8; r++)
        bfr[r] = (short)Vb[(8 * lk + r) * 64 + 16 * q + lrow];
      pacc[q] = __builtin_amdgcn_mfma_f32_16x16x32_bf16(afr, bfr, pacc[q], 0, 0, 0);
    }

    __syncthreads();  // drains vmcnt (prefetch landed) + publishes buf^1;
                      // also releases buf[cur] for overwrite next iteration
    cur ^= 1;
  }

  // epilogue: publish 1/s per row (rows 4d+lk), read per PV layout (4lk+r)
  if (lrow == 0) {
#pragma unroll
    for (int d = 0; d < 4; d++) Fs[w][4 * d + lk] = (float)(1.0 / sacc[d]);
  }
  f32x4 sv = *(const f32x4*)&Fs[w][4 * lk];
#pragma unroll
  for (int q = 0; q < 4; q++)
#pragma unroll
    for (int r = 0; r < 4; r++) {
      int row = 16 * w + 4 * lk + r;
      O[((size_t)(b * Ls + l0 + row)) * Dd + h * HDm + 16 * q + lrow] =
          pacc[q][r] * sv[r];
    }
  // stash final ref + sum per row (rows 4d+lk, writers lrow==0)
  if (lrow == 0) {
#pragma unroll
    for (int d = 0; d < 4; d++) {
      int row = 16 * w + 4 * d + lk;
      float* mrow = (float*)(Qd + ((size_t)(b * Ls + l0 + row)) * Dd + h * HDm);
      mrow[64] = mreff[d];
      *(double*)(mrow + 66) = sacc[d];
    }
  }
}

// ---------------------------------------------------------------------------
// Rescale: p = p~ * exp(ref_t - ref_final) / s. One block per attention row.
// ---------------------------------------------------------------------------
__global__ __launch_bounds__(256) void attn_scale(
    float* __restrict__ attn, const double* __restrict__ Qd) {
  int R = blockIdx.x;                 // 0..131071: ((b*Hh+h)*Ls + l)
  int b = R >> 15;
  int rem = R & 32767;
  int h = rem >> 11;
  int l = rem & 2047;
  const float* mrow = (const float*)(Qd + ((size_t)(b * Ls + l)) * Dd + h * HDm);
  int tid = threadIdx.x;
  int kt = tid >> 2;                  // 8 cols per thread, within one 32-col tile
  double mt = (double)mrow[kt];
  double mf = (double)mrow[64];
  double s = *(const double*)(mrow + 66);
  float sc = (float)(exp(mt - mf) / s);
  float4* ap = (float4*)(attn + (size_t)R * Ls + tid * 8);
  float4 a0 = ap[0], a1 = ap[1];
  a0.x *= sc; a0.y *= sc; a0.z *= sc; a0.w *= sc;
  a1.x *= sc; a1.y *= sc; a1.z *= sc; a1.w *= sc;
  ap[0] = a0; ap[1] = a1;
}

// ---------------------------------------------------------------------------
extern "C" void kernel_launch(void* const* d_in, const int* in_sizes, int n_in,
                              void* d_out, int out_size, void* d_ws, size_t ws_size,
                              hipStream_t stream) {
  const float* query = (const float*)d_in[0];
  const float* key   = (const float*)d_in[1];
  const float* value = (const float*)d_in[2];
  const float* Wq    = (const float*)d_in[3];
  const float* Wk    = (const float*)d_in[4];
  const float* Wv    = (const float*)d_in[5];
  const float* Wo    = (const float*)d_in[6];
  const float* bo    = (const float*)d_in[7];

  float* out0 = (float*)d_out;            // [B,L,D]
  float* attn = out0 + (size_t)ML * Dd;   // [B,H,L,L]

  // ws: Qd (64MB f64) | Kd (64MB f64) | Vfb (16MB bf16) | Of (32MB f32)
  char* ws = (char*)d_ws;
  double* Qd  = (double*)ws;
  double* Kd  = (double*)(ws + (size_t)ML * Dd * 8);
  u16*    Vfb = (u16*)(ws + (size_t)ML * Dd * 16);
  float*  Of  = (float*)(ws + (size_t)ML * Dd * 16 + (size_t)ML * Dd * 2);

  dim3 gemm_grid(Dd / 64, ML / 64);
  // Q pre-scaled by softmax 1/sqrt(64) = 0.125 (exact pow2 -> logits
  // bit-identical to post-scaling)
  gemm_nt_mfma_f64<<<gemm_grid, 256, 0, stream>>>(query, Wq, Qd, 0.125);
  gemm_nt_mfma_f64<<<gemm_grid, 256, 0, stream>>>(key,   Wk, Kd, 1.0);
  gemm_nt_mfma_bf16o<<<gemm_grid, 256, 0, stream>>>(value, Wv, Vfb);

  attn_flash<<<Bb * Hh * (Ls / 64), 256, 0, stream>>>(Qd, Kd, Vfb, attn, Of);
  attn_scale<<<Bb * Hh * Ls, 256, 0, stream>>>(attn, Qd);

  gemm_nt_mfma_f32<<<gemm_grid, 256, 0, stream>>>(Of, Wo, bo, out0);
}

// Round 9
// 3458.946 us; speedup vs baseline: 1.6566x; 1.1474x over previous
//
#include <hip/hip_runtime.h>
#include <math.h>

#define Bb 4
#define Ls 2048
#define Dd 1024
#define Hh 16
#define HDm 64
#define ML (Bb*Ls)   /* 8192 rows */

typedef double f64x4 __attribute__((ext_vector_type(4)));
typedef float  f32x4 __attribute__((ext_vector_type(4)));
typedef short  bf16x8 __attribute__((ext_vector_type(8)));
typedef unsigned int u32;
typedef unsigned short u16;

// HBM -> LDS direct (no VGPR round-trip). LDS dest = wave-uniform base +
// lane*16 (m104); global src is per-lane. size must be literal 16 (m97).
__device__ __forceinline__ void gload16(const void* g, void* l) {
  __builtin_amdgcn_global_load_lds(
      (const __attribute__((address_space(1))) u32*)g,
      (__attribute__((address_space(3))) u32*)l, 16, 0, 0);
}

// f32 -> bf16, round-to-nearest-even (finite inputs only)
__device__ __forceinline__ u16 f2bf(float f) {
  u32 u = __float_as_uint(f);
  u += 0x7FFFu + ((u >> 16) & 1u);
  return (u16)(u >> 16);
}

// ---------------------------------------------------------------------------
// f32 -> bf16 elementwise (operand pre-conversion for bf16 GEMMs).
// ---------------------------------------------------------------------------
__global__ __launch_bounds__(256) void f32_to_bf16(
    const float* __restrict__ in, u16* __restrict__ out, int n8) {
  int i = blockIdx.x * 256 + threadIdx.x;
  if (i >= n8) return;
  const float4* p = (const float4*)(in + (size_t)i * 8);
  float4 a = p[0], c = p[1];
  union { u16 h[8]; uint4 v; } o;
  o.h[0] = f2bf(a.x); o.h[1] = f2bf(a.y); o.h[2] = f2bf(a.z); o.h[3] = f2bf(a.w);
  o.h[4] = f2bf(c.x); o.h[5] = f2bf(c.y); o.h[6] = f2bf(c.z); o.h[7] = f2bf(c.w);
  *(uint4*)(out + (size_t)i * 8) = o.v;
}

// ---------------------------------------------------------------------------
// Shared NT GEMM core via f64 MFMA (round-8 version, passed, absmax 48).
// ROUND-8 FINDING: double-buffering was NEUTRAL vs serial (both ~560us) ->
// the k-step COMPUTE phase is the wall; implied rate 30.7 TF ~= f64 MFMA at
// half the nominal 78.6 TF (CDNA4 halved f64 matrix rate). f64 GEMMs are
// near their pipe ceiling; only Q/K projections remain on this path
// (logit top-2 gap min ~O(20-50) abs of sigma 9e6 -> f64 mandatory there).
// MFMA f64 16x16x4 layouts (validated round 2): A row=lane&15, k=lane>>4;
// B col=lane&15, k=lane>>4; D row=4*reg+(lane>>4), col=lane&15.
// ---------------------------------------------------------------------------
__device__ __forceinline__ void gemm_core_nt(
    const float* __restrict__ A, const float* __restrict__ B,
    int bm, int bn, int w, int lrow, int lk, f64x4 acc[4]) {
  const int K = Dd;
  __shared__ __align__(16) float As[2][64 * 16];
  __shared__ __align__(16) float Bs[2][64 * 16];
  const int tid = threadIdx.x;
  const int r = tid >> 2, blk = tid & 3;       // staging coords (per-lane)
  const int sblk = blk ^ ((r >> 1) & 3);       // write-side swizzle
  const int sxw = ((lrow >> 1) & 3) << 2;      // read-side swizzle (involution)
  const float* ga = A + (size_t)(bm + r) * K + 4 * sblk;
  const float* gb = B + (size_t)(bn + r) * K + 4 * sblk;

#pragma unroll
  for (int j = 0; j < 4; j++) acc[j] = (f64x4){0., 0., 0., 0.};

  // wave-uniform LDS bases (HW adds lane*16)
  char* la0 = (char*)&As[0][0] + w * 1024;
  char* lb0 = (char*)&Bs[0][0] + w * 1024;
  char* la1 = (char*)&As[1][0] + w * 1024;
  char* lb1 = (char*)&Bs[1][0] + w * 1024;

  gload16(ga, la0);
  gload16(gb, lb0);
  __syncthreads();   // drains vmcnt: tile 0 resident

  int cur = 0;
  for (int k0 = 16; k0 <= K; k0 += 16) {
    if (k0 < K) {                       // prefetch tile k0 into buf^1
      gload16(ga + k0, cur ? la0 : la1);
      gload16(gb + k0, cur ? lb0 : lb1);
    }
    const float* Abuf = &As[cur][0];
    const float* Bbuf = &Bs[cur][0];
#pragma unroll
    for (int t = 0; t < 4; t++) {
      double a = (double)Abuf[(16 * w + lrow) * 16 + ((4 * t + lk) ^ sxw)];
#pragma unroll
      for (int j = 0; j < 4; j++) {
        double bv = (double)Bbuf[(16 * j + lrow) * 16 + ((4 * t + lk) ^ sxw)];
        acc[j] = __builtin_amdgcn_mfma_f64_16x16x4f64(a, bv, acc[j], 0, 0, 0);
      }
    }
    __syncthreads();  // drains vmcnt (prefetch landed) + releases buf[cur]
    cur ^= 1;
  }
}

__global__ __launch_bounds__(256) void gemm_nt_mfma_f64(
    const float* __restrict__ A, const float* __restrict__ B,
    double* __restrict__ C, double outscale) {
  const int tid = threadIdx.x;
  const int lane = tid & 63;
  const int w = tid >> 6;
  const int lrow = lane & 15, lk = lane >> 4;
  const int bm = blockIdx.y * 64, bn = blockIdx.x * 64;
  f64x4 acc[4];
  gemm_core_nt(A, B, bm, bn, w, lrow, lk, acc);
#pragma unroll
  for (int j = 0; j < 4; j++)
#pragma unroll
    for (int d = 0; d < 4; d++) {
      size_t m = (size_t)(bm + 16 * w + 4 * d + lk);
      C[m * Dd + bn + 16 * j + lrow] = acc[j][d] * outscale;
    }
}

// ---------------------------------------------------------------------------
// NT GEMM on the bf16 matrix pipe: C = A @ B^T, A/B pre-converted bf16,
// f32 accumulate (mfma_f32_16x16x32_bf16; frag layouts validated by attn PV:
// A row=lane&15,k=8*(lane>>4)+j; B col=lane&15, same k; D col=lane&15,
// row=4*(lane>>4)+reg). 64x64 tile, K-step 32, double-buffered gload16
// (1KB/wave for A + B each). Output bf16 (Cb) or f32+bias (Cf).
// Used for V projection and out0 -- paths with no f64 precision need
// (V is rounded to bf16 before PV anyway; out0 slack ~64 >> added ~4-8).
// ---------------------------------------------------------------------------
__global__ __launch_bounds__(256) void gemm_nt_bf16(
    const u16* __restrict__ A, const u16* __restrict__ B,
    const float* __restrict__ bias, u16* __restrict__ Cb,
    float* __restrict__ Cf) {
  const int K = Dd;
  __shared__ __align__(16) u16 Asb[2][64 * 32];
  __shared__ __align__(16) u16 Bsb[2][64 * 32];
  const int tid = threadIdx.x;
  const int lane = tid & 63;
  const int w = tid >> 6;
  const int lrow = lane & 15, lk = lane >> 4;
  const int bm = blockIdx.y * 64, bn = blockIdx.x * 64;

  // staging: wave w stages rows 16w..16w+15 (A and B); lane covers
  // row 16w+(lane>>2), 16B group lane&3 -> LDS linear [row][32] bf16
  const int srow = 16 * w + (lane >> 2);
  const u16* ga = A + (size_t)(bm + srow) * K + 8 * (lane & 3);
  const u16* gb = B + (size_t)(bn + srow) * K + 8 * (lane & 3);
  char* la0 = (char*)&Asb[0][0] + w * 1024;
  char* lb0 = (char*)&Bsb[0][0] + w * 1024;
  char* la1 = (char*)&Asb[1][0] + w * 1024;
  char* lb1 = (char*)&Bsb[1][0] + w * 1024;

  f32x4 acc[4] = {{0.f,0.f,0.f,0.f},{0.f,0.f,0.f,0.f},
                  {0.f,0.f,0.f,0.f},{0.f,0.f,0.f,0.f}};

  gload16(ga, la0);
  gload16(gb, lb0);
  __syncthreads();

  int cur = 0;
  for (int k0 = 32; k0 <= K; k0 += 32) {
    if (k0 < K) {
      gload16(ga + k0, cur ? la0 : la1);
      gload16(gb + k0, cur ? lb0 : lb1);
    }
    const u16* Ab = &Asb[cur][0];
    const u16* Bt = &Bsb[cur][0];
    bf16x8 afr = *(const bf16x8*)&Ab[(16 * w + lrow) * 32 + 8 * lk];
#pragma unroll
    for (int j = 0; j < 4; j++) {
      bf16x8 bfr = *(const bf16x8*)&Bt[(16 * j + lrow) * 32 + 8 * lk];
      acc[j] = __builtin_amdgcn_mfma_f32_16x16x32_bf16(afr, bfr, acc[j], 0, 0, 0);
    }
    __syncthreads();
    cur ^= 1;
  }

  // D: col = 16j + lrow, row = 16w + 4*lk + r
#pragma unroll
  for (int j = 0; j < 4; j++)
#pragma unroll
    for (int r = 0; r < 4; r++) {
      size_t m = (size_t)(bm + 16 * w + 4 * lk + r);
      int n = bn + 16 * j + lrow;
      float v = acc[j][r];
      if (bias) v += bias[n];
      if (Cf) Cf[m * Dd + n] = v;
      else    Cb[m * Dd + n] = f2bf(v);
    }
}

// ---------------------------------------------------------------------------
// One-sweep flash attention, v8b: identical to v8 (1380us, absmax 48) except
// O is written as bf16 (feeds the bf16 out0 GEMM; one extra rounding of the
// normalized O, ~4 abs through Wo).
// LDS: Kbuf 32768 + Vb 8192 + Pb 4096 + Fs 256 = 45312 -> 3 blocks/CU.
// ---------------------------------------------------------------------------
__global__ __launch_bounds__(256) void attn_flash(
    double* __restrict__ Qd, const double* __restrict__ Kd,
    const u16* __restrict__ Vf, float* __restrict__ attn,
    u16* __restrict__ O) {
  __shared__ __align__(16) double Kbuf[2][32 * 64];
  __shared__ __align__(16) u16    Vb16[2][32 * 64];  // [key][dim] bf16
  __shared__ __align__(16) u16    Pb[4][16 * 32];    // per-wave [row][key] bf16
  __shared__ __align__(16) float  Fs[4][16];         // per-wave per-row scalar

  const int tid = threadIdx.x;
  const int lane = tid & 63;
  const int w = tid >> 6;             // wave 0..3 -> q-row strip 16w
  const int lrow = lane & 15;         // A-row / B,D-col index
  const int lk = lane >> 4;           // k-group index / D row bits
  const int blk = blockIdx.x;
  const int qt = blk & 31;            // 32 q-tiles of 64 rows
  const int h = (blk >> 5) & 15;      // head
  const int b = blk >> 9;
  const int l0 = qt * 64;

  const double* Qg = Qd + ((size_t)(b * Ls + l0)) * Dd + h * HDm;
  const double* Kg = Kd + ((size_t)b * Ls) * Dd + h * HDm;
  const u16*    Vg = Vf + ((size_t)b * Ls) * Dd + h * HDm;
  float* aout = attn + ((size_t)((b * Hh + h) * Ls + l0)) * Ls;

  // Q fragments: lane holds Q[16w+lrow][4t+lk] for t=0..15 (whole sweep);
  // Qd is pre-scaled by 0.125 at projection time.
  double qreg[16];
#pragma unroll
  for (int t = 0; t < 16; t++)
    qreg[t] = Qg[(size_t)(16 * w + lrow) * Dd + 4 * t + lk];

  // K staging geometry (v7, validated): linear [32][64] f64 with XOR swizzle
  // byte^=(row&7)<<4 on BOTH sides (pre-swizzled global src + XOR'd read).
  const int l16 = (lane & 31) * 16;
  const int halfk = lane >> 5;
  const int sx = (lrow & 7) << 1;     // K read swizzle (element units)

  auto stage = [&](int kts, int bsel) {
#pragma unroll
    for (int jj = 0; jj < 4; jj++) {
      int i = w + 4 * jj;
      int row = 2 * i + halfk;
      int inner = l16 ^ ((row & 7) << 4);   // pre-swizzled global source
      const char* g = (const char*)Kg + (((size_t)(kts * 32 + row)) << 13) + inner;
      gload16(g, (char*)(&Kbuf[bsel][0]) + i * 1024);
    }
    // V: wave w stages keys 8w..8w+7 bf16 (1KB); lane: key 8w+(lane>>3),
    // dims 8*(lane&7).. -> LDS linear [key][64] bf16
    {
      const char* g = (const char*)Vg +
          ((size_t)(kts * 32 + 8 * w + (lane >> 3))) * (Dd * 2) + (lane & 7) * 16;
      gload16(g, (char*)(&Vb16[bsel][0]) + w * 1024);
    }
  };

  float mreff[4];
  double sacc[4];
  f32x4 pacc[4];   // PV accum per dim-quadrant; D: col=lrow, row=4*lk+reg
#pragma unroll
  for (int d = 0; d < 4; d++) {
    mreff[d] = -INFINITY;
    sacc[d] = 0.0;
    pacc[d] = (f32x4){0.f, 0.f, 0.f, 0.f};
  }

  stage(0, 0);
  __syncthreads();   // drains vmcnt(0): tile 0 resident for all waves

  int cur = 0;
  for (int kt = 0; kt < 64; kt++) {
    if (kt < 63) stage(kt + 1, cur ^ 1);   // async: lands during compute

    const double* Kb = &Kbuf[cur][0];

    // QK^T: E[r][c] = sum_k Q[r][k] K[c][k]; quadrant 0: keys 0-15, 1: 16-31
    f64x4 acc0 = {0.0, 0.0, 0.0, 0.0};
    f64x4 acc1 = {0.0, 0.0, 0.0, 0.0};
#pragma unroll
    for (int t = 0; t < 16; t++) {
      int ko = (4 * t + lk) ^ sx;
      double b0 = Kb[lrow * 64 + ko];
      double b1 = Kb[(16 + lrow) * 64 + ko];
      acc0 = __builtin_amdgcn_mfma_f64_16x16x4f64(qreg[t], b0, acc0, 0, 0, 0);
      acc1 = __builtin_amdgcn_mfma_f64_16x16x4f64(qreg[t], b1, acc1, 0, 0, 0);
    }

    // online softmax per owned row: acc[d] is row 4*d + lk (f64 D layout),
    // col lrow (acc0) / 16+lrow (acc1). Logits pre-scaled via Q.
#pragma unroll
    for (int d = 0; d < 4; d++) {
      double e0 = acc0[d];
      double e1 = acc1[d];
      float tmf = fmaxf((float)e0, (float)e1);
#pragma unroll
      for (int m = 1; m < 16; m <<= 1) tmf = fmaxf(tmf, __shfl_xor(tmf, m));
      float mo_f = mreff[d];
      float ref_f = fmaxf(mo_f, tmf);        // float-rounded running ref
      double ref = (double)ref_f;
      float p0 = expf((float)(e0 - ref));
      float p1 = expf((float)(e1 - ref));
      double ts = (double)p0 + (double)p1;
#pragma unroll
      for (int m = 1; m < 16; m <<= 1) ts += __shfl_xor(ts, m);
      float factor = expf(mo_f - ref_f);     // <= 1
      sacc[d] = sacc[d] * (double)factor + ts;
      mreff[d] = ref_f;
      int row = 16 * w + 4 * d + lk;
      aout[(size_t)row * Ls + kt * 32 + lrow] = p0;
      aout[(size_t)row * Ls + kt * 32 + 16 + lrow] = p1;
      if (lrow == 0) {  // stash per-(row,tile) ref; publish rescale factor
        ((float*)(Qd + ((size_t)(b * Ls + l0 + row)) * Dd + h * HDm))[kt] = ref_f;
        Fs[w][4 * d + lk] = factor;
      }
      // P tile in A-operand layout: Pb[row 4d+lk][key] bf16
      Pb[w][(4 * d + lk) * 32 + lrow] = f2bf(p0);
      Pb[w][(4 * d + lk) * 32 + 16 + lrow] = f2bf(p1);
    }

    // PV on matrix pipe (wave-internal LDS order: reads see writes above).
    // A frag: P[row=lrow][k=8*lk+j] = one b128 from Pb.
    bf16x8 afr = *(const bf16x8*)&Pb[w][lrow * 32 + 8 * lk];
    f32x4 fv = *(const f32x4*)&Fs[w][4 * lk];   // factors for rows 4lk+0..3
    const u16* Vb = &Vb16[cur][0];
#pragma unroll
    for (int q = 0; q < 4; q++) {
      pacc[q][0] *= fv[0];
      pacc[q][1] *= fv[1];
      pacc[q][2] *= fv[2];
      pacc[q][3] *= fv[3];
      bf16x8 bfr;  // B frag: V[k=8*lk+r][col=16q+lrow]
#pragma unroll
      for (int r = 0; r < 8; r++)
        bfr[r] = (short)Vb[(8 * lk + r) * 64 + 16 * q + lrow];
      pacc[q] = __builtin_amdgcn_mfma_f32_16x16x32_bf16(afr, bfr, pacc[q], 0, 0, 0);
    }

    __syncthreads();  // drains vmcnt (prefetch landed) + publishes buf^1;
                      // also releases buf[cur] for overwrite next iteration
    cur ^= 1;
  }

  // epilogue: publish 1/s per row (rows 4d+lk), read per PV layout (4lk+r)
  if (lrow == 0) {
#pragma unroll
    for (int d = 0; d < 4; d++) Fs[w][4 * d + lk] = (float)(1.0 / sacc[d]);
  }
  f32x4 sv = *(const f32x4*)&Fs[w][4 * lk];
#pragma unroll
  for (int q = 0; q < 4; q++)
#pragma unroll
    for (int r = 0; r < 4; r++) {
      int row = 16 * w + 4 * lk + r;
      O[((size_t)(b * Ls + l0 + row)) * Dd + h * HDm + 16 * q + lrow] =
          f2bf(pacc[q][r] * sv[r]);
    }
  // stash final ref + sum per row (rows 4d+lk, writers lrow==0)
  if (lrow == 0) {
#pragma unroll
    for (int d = 0; d < 4; d++) {
      int row = 16 * w + 4 * d + lk;
      float* mrow = (float*)(Qd + ((size_t)(b * Ls + l0 + row)) * Dd + h * HDm);
      mrow[64] = mreff[d];
      *(double*)(mrow + 66) = sacc[d];
    }
  }
}

// ---------------------------------------------------------------------------
// Rescale: p = p~ * exp(ref_t - ref_final) / s. One block per attention row.
// ---------------------------------------------------------------------------
__global__ __launch_bounds__(256) void attn_scale(
    float* __restrict__ attn, const double* __restrict__ Qd) {
  int R = blockIdx.x;                 // 0..131071: ((b*Hh+h)*Ls + l)
  int b = R >> 15;
  int rem = R & 32767;
  int h = rem >> 11;
  int l = rem & 2047;
  const float* mrow = (const float*)(Qd + ((size_t)(b * Ls + l)) * Dd + h * HDm);
  int tid = threadIdx.x;
  int kt = tid >> 2;                  // 8 cols per thread, within one 32-col tile
  double mt = (double)mrow[kt];
  double mf = (double)mrow[64];
  double s = *(const double*)(mrow + 66);
  float sc = (float)(exp(mt - mf) / s);
  float4* ap = (float4*)(attn + (size_t)R * Ls + tid * 8);
  float4 a0 = ap[0], a1 = ap[1];
  a0.x *= sc; a0.y *= sc; a0.z *= sc; a0.w *= sc;
  a1.x *= sc; a1.y *= sc; a1.z *= sc; a1.w *= sc;
  ap[0] = a0; ap[1] = a1;
}

// ---------------------------------------------------------------------------
extern "C" void kernel_launch(void* const* d_in, const int* in_sizes, int n_in,
                              void* d_out, int out_size, void* d_ws, size_t ws_size,
                              hipStream_t stream) {
  const float* query = (const float*)d_in[0];
  const float* key   = (const float*)d_in[1];
  const float* value = (const float*)d_in[2];
  const float* Wq    = (const float*)d_in[3];
  const float* Wk    = (const float*)d_in[4];
  const float* Wv    = (const float*)d_in[5];
  const float* Wo    = (const float*)d_in[6];
  const float* bo    = (const float*)d_in[7];

  float* out0 = (float*)d_out;            // [B,L,D]
  float* attn = out0 + (size_t)ML * Dd;   // [B,H,L,L]

  // ws layout (bytes):
  //   Qd 64MB | Kd 64MB | Vfb 16MB | Ofb 16MB | valb 16MB | Wvb 2MB | Wob 2MB
  char* ws = (char*)d_ws;
  double* Qd   = (double*)ws;
  double* Kd   = (double*)(ws + (size_t)ML * Dd * 8);
  u16*    Vfb  = (u16*)(ws + (size_t)ML * Dd * 16);
  u16*    Ofb  = (u16*)(ws + (size_t)ML * Dd * 16 + (size_t)ML * Dd * 2);
  u16*    valb = (u16*)(ws + (size_t)ML * Dd * 16 + (size_t)ML * Dd * 4);
  u16*    Wvb  = (u16*)(ws + (size_t)ML * Dd * 16 + (size_t)ML * Dd * 6);
  u16*    Wob  = (u16*)(ws + (size_t)ML * Dd * 16 + (size_t)ML * Dd * 6
                           + (size_t)Dd * Dd * 2);

  dim3 gemm_grid(Dd / 64, ML / 64);

  // operand pre-conversion for bf16 GEMM paths
  f32_to_bf16<<<(ML * Dd / 8) / 256, 256, 0, stream>>>(value, valb, ML * Dd / 8);
  f32_to_bf16<<<(Dd * Dd / 8) / 256, 256, 0, stream>>>(Wv, Wvb, Dd * Dd / 8);
  f32_to_bf16<<<(Dd * Dd / 8) / 256, 256, 0, stream>>>(Wo, Wob, Dd * Dd / 8);

  // Q pre-scaled by softmax 1/sqrt(64) = 0.125 (exact pow2 -> logits
  // bit-identical to post-scaling). Q/K MUST be f64 (argmax gaps ~20-50).
  gemm_nt_mfma_f64<<<gemm_grid, 256, 0, stream>>>(query, Wq, Qd, 0.125);
  gemm_nt_mfma_f64<<<gemm_grid, 256, 0, stream>>>(key,   Wk, Kd, 1.0);

  // V projection on bf16 matrix pipe (V is bf16-rounded before PV anyway)
  gemm_nt_bf16<<<gemm_grid, 256, 0, stream>>>(valb, Wvb, nullptr, Vfb, nullptr);

  attn_flash<<<Bb * Hh * (Ls / 64), 256, 0, stream>>>(Qd, Kd, Vfb, attn, Ofb);
  attn_scale<<<Bb * Hh * Ls, 256, 0, stream>>>(attn, Qd);

  // out0 = Of @ Wo^T + bo on bf16 matrix pipe, f32 out
  gemm_nt_bf16<<<gemm_grid, 256, 0, stream>>>(Ofb, Wob, bo, nullptr, out0);
}